// Round 1
// baseline (572.013 us; speedup 1.0000x reference)
//
#include <hip/hip_runtime.h>
#include <hip/hip_bf16.h>
#include <cstdint>

#define Bz 2
#define Tz 2048
#define Dz 1024
#define Hz 16
#define NR (Bz*Tz)   // 4096 rows

typedef __bf16 bf16;
typedef __bf16 bf16x8 __attribute__((ext_vector_type(8)));
typedef __bf16 bf16x4 __attribute__((ext_vector_type(4)));
typedef short  s16x4  __attribute__((ext_vector_type(4)));
typedef float  f32x4  __attribute__((ext_vector_type(4)));

typedef unsigned int u32as1 __attribute__((address_space(1)));
typedef unsigned int u32as3 __attribute__((address_space(3)));

__device__ __forceinline__ void gl2lds16(const void* gp, void* lp) {
    __builtin_amdgcn_global_load_lds((u32as1*)gp, (u32as3*)lp, 16, 0, 0);
}

// ---------------- transpose + f32->bf16 cast: W[K][N] -> WT[N][K] ----------------
__global__ void k_transpose_cvt(const float* __restrict__ W, bf16* __restrict__ WT,
                                int K, int N) {
    __shared__ float tile[32][33];
    const int n0 = blockIdx.x * 32, k0 = blockIdx.y * 32;
    const int tx = threadIdx.x, ty = threadIdx.y;   // (32,8)
#pragma unroll
    for (int i = 0; i < 4; i++)
        tile[ty + i*8][tx] = W[(size_t)(k0 + ty + i*8) * N + n0 + tx];
    __syncthreads();
#pragma unroll
    for (int i = 0; i < 4; i++)
        WT[(size_t)(n0 + ty + i*8) * K + k0 + tx] = (bf16)tile[tx][ty + i*8];
}

// ---------------- LayerNorm (ddof=1 std, eps added to std) -> bf16 ----------------
__global__ void k_layernorm(const float* __restrict__ X, const float* __restrict__ gam,
                            const float* __restrict__ bet, bf16* __restrict__ out) {
    const int row = blockIdx.x, t = threadIdx.x;   // 256 threads, D=1024
    const float4 v = ((const float4*)(X + (size_t)row * Dz))[t];
    float s  = v.x + v.y + v.z + v.w;
    float ss = v.x*v.x + v.y*v.y + v.z*v.z + v.w*v.w;
#pragma unroll
    for (int o = 1; o < 64; o <<= 1) { s += __shfl_xor(s, o); ss += __shfl_xor(ss, o); }
    __shared__ float rs[4], rss[4];
    if ((t & 63) == 0) { rs[t >> 6] = s; rss[t >> 6] = ss; }
    __syncthreads();
    s  = rs[0] + rs[1] + rs[2] + rs[3];
    ss = rss[0] + rss[1] + rss[2] + rss[3];
    const float mean = s * (1.f / Dz);
    const float var  = fmaxf((ss - s * mean) * (1.f / (Dz - 1)), 0.f);
    const float inv  = 1.f / (sqrtf(var) + 1e-6f);
    const float4 gv = ((const float4*)gam)[t];
    const float4 bv = ((const float4*)bet)[t];
    bf16x4 o;
    o[0] = (bf16)((v.x - mean) * gv.x * inv + bv.x);
    o[1] = (bf16)((v.y - mean) * gv.y * inv + bv.y);
    o[2] = (bf16)((v.z - mean) * gv.z * inv + bv.z);
    o[3] = (bf16)((v.w - mean) * gv.w * inv + bv.w);
    *(bf16x4*)(out + (size_t)row * Dz + t * 4) = o;
}

// ---------------- generic bf16 GEMM: C[M][N] = A[M][K] * BT[N][K]^T ----------------
// 128x128 tile, BK=64, 4 waves (2x2), each wave 4x4 MFMA 16x16x32 tiles.
// global_load_lds width=16 staging; XOR column swizzle (16B units) for conflict-free
// ds_read_b128. Epilogue: +bias, optional exact GELU, +residual, f32 or bf16 store.
__global__ __launch_bounds__(256) void k_gemm(
    const bf16* __restrict__ A, const bf16* __restrict__ BT,
    int M, int N, int K,
    const float* __restrict__ bias, const float* __restrict__ resid,
    float* __restrict__ Cf, bf16* __restrict__ Cb, int act)
{
    __shared__ bf16 lA[128 * 64];
    __shared__ bf16 lB[128 * 64];
    const int tid = threadIdx.x;
    const int w = tid >> 6, lane = tid & 63;
    const int q = lane >> 4, l16 = lane & 15;
    const int m0 = blockIdx.y * 128, n0 = blockIdx.x * 128;
    const int wm = (w >> 1) * 64, wn = (w & 1) * 64;

    // staging: LDS linear layout, lane covers 16B; row = w*32 + i*8 + lane/8
    // swizzled col-slot content: slot csw holds global kg = csw ^ (row&7)
    const int srow = lane >> 3;                 // 0..7
    const int skg  = (lane & 7) ^ srow;         // kg fetched by this lane (all i)
    const bf16* Ab = A  + (size_t)(m0 + w * 32 + srow) * K + skg * 8;
    const bf16* Bb = BT + (size_t)(n0 + w * 32 + srow) * K + skg * 8;
    bf16* lAw = lA + w * 2048;
    bf16* lBw = lB + w * 2048;

    f32x4 acc[4][4] = {};

    for (int k0 = 0; k0 < K; k0 += 64) {
#pragma unroll
        for (int i = 0; i < 4; i++) {
            gl2lds16(Ab + (size_t)i * 8 * K + k0, lAw + i * 512);
            gl2lds16(Bb + (size_t)i * 8 * K + k0, lBw + i * 512);
        }
        __syncthreads();
#pragma unroll
        for (int kh = 0; kh < 2; kh++) {
            const int sl = (((kh * 4 + q) ^ (l16 & 7)) * 8);  // swizzled, in elements
            bf16x8 af[4], bfr[4];
#pragma unroll
            for (int t = 0; t < 4; t++) {
                af[t]  = *(const bf16x8*)(lA + (wm + t * 16 + l16) * 64 + sl);
                bfr[t] = *(const bf16x8*)(lB + (wn + t * 16 + l16) * 64 + sl);
            }
#pragma unroll
            for (int i = 0; i < 4; i++)
#pragma unroll
                for (int j = 0; j < 4; j++)
                    acc[i][j] = __builtin_amdgcn_mfma_f32_16x16x32_bf16(
                        af[i], bfr[j], acc[i][j], 0, 0, 0);
        }
        __syncthreads();
    }

    // epilogue: C/D layout col=lane&15, row=quad*4+reg
#pragma unroll
    for (int i = 0; i < 4; i++) {
        const int gr = m0 + wm + i * 16 + q * 4;
#pragma unroll
        for (int j = 0; j < 4; j++) {
            const int gc = n0 + wn + j * 16 + l16;
            const float bv = bias ? bias[gc] : 0.f;
#pragma unroll
            for (int r = 0; r < 4; r++) {
                float v = acc[i][j][r] + bv;
                if (act) v = 0.5f * v * (1.f + erff(v * 0.70710678118f));
                const size_t idx = (size_t)(gr + r) * N + gc;
                if (resid) v += resid[idx];
                if (Cf) Cf[idx] = v;
                else    Cb[idx] = (bf16)v;
            }
        }
    }
}

// ---------------- flash attention, causal, scale folded post-QK ----------------
// qkv: [NR][3072] bf16 (q|k|v, each head 64 contiguous). ctx: [NR][1024] bf16.
// Per wave: 16 q rows. S^T = K*Q^T via mfma_16x16x32 (C-layout: row=key, col=q),
// softmax per column (in-lane 4 regs + shfl_xor 16/32), P^T stays in regs as the
// B-operand of mfma_16x16x16bf16_1k; O^T accumulates in C-layout.
__global__ __launch_bounds__(256) void k_attn(const bf16* __restrict__ qkv,
                                              bf16* __restrict__ ctx)
{
    const int tid = threadIdx.x, w = tid >> 6, lane = tid & 63;
    const int q16 = lane & 15, quad = lane >> 4;
    const int qblk = (gridDim.x - 1 - blockIdx.x);      // heavy blocks first
    const int qt = qblk * 64 + w * 16;
    const int h = blockIdx.y, b = blockIdx.z;
    const bf16* base = qkv + (size_t)b * Tz * 3072;
    const bf16* Qp = base + h * 64;
    const bf16* Kp = base + 1024 + h * 64;
    const bf16* Vp = base + 2048 + h * 64;

    const bf16x8 qf0 = *(const bf16x8*)(Qp + (size_t)(qt + q16) * 3072 + quad * 8);
    const bf16x8 qf1 = *(const bf16x8*)(Qp + (size_t)(qt + q16) * 3072 + 32 + quad * 8);

    f32x4 acc[4] = {};
    float m_i = -1e30f, l_i = 0.f;

    for (int kt = 0; kt <= qt; kt += 16) {
        const bf16x8 kf0 = *(const bf16x8*)(Kp + (size_t)(kt + q16) * 3072 + quad * 8);
        const bf16x8 kf1 = *(const bf16x8*)(Kp + (size_t)(kt + q16) * 3072 + 32 + quad * 8);
        f32x4 s = {0.f, 0.f, 0.f, 0.f};
        s = __builtin_amdgcn_mfma_f32_16x16x32_bf16(kf0, qf0, s, 0, 0, 0);
        s = __builtin_amdgcn_mfma_f32_16x16x32_bf16(kf1, qf1, s, 0, 0, 0);

        float sv[4];
#pragma unroll
        for (int r = 0; r < 4; r++) {
            const float x = s[r] * 0.125f;                       // 1/sqrt(64)
            sv[r] = (kt + quad * 4 + r > qt + q16) ? -1e30f : x; // causal
        }
        float tm = fmaxf(fmaxf(sv[0], sv[1]), fmaxf(sv[2], sv[3]));
        tm = fmaxf(tm, __shfl_xor(tm, 16));
        tm = fmaxf(tm, __shfl_xor(tm, 32));
        const float m_new = fmaxf(m_i, tm);
        const float alpha = __expf(m_i - m_new);
        float ts = 0.f;
        bf16x4 pb;
#pragma unroll
        for (int r = 0; r < 4; r++) {
            const float pe = __expf(sv[r] - m_new);
            ts += pe;
            pb[r] = (bf16)pe;
        }
        ts += __shfl_xor(ts, 16);
        ts += __shfl_xor(ts, 32);
        l_i = l_i * alpha + ts;
        m_i = m_new;
        const s16x4 pf = __builtin_bit_cast(s16x4, pb);
#pragma unroll
        for (int vt = 0; vt < 4; vt++) {
#pragma unroll
            for (int r = 0; r < 4; r++) acc[vt][r] *= alpha;
            bf16x4 vv;
#pragma unroll
            for (int j = 0; j < 4; j++)
                vv[j] = Vp[(size_t)(kt + quad * 4 + j) * 3072 + vt * 16 + q16];
            const s16x4 vf = __builtin_bit_cast(s16x4, vv);
            acc[vt] = __builtin_amdgcn_mfma_f32_16x16x16bf16_1k(vf, pf, acc[vt], 0, 0, 0);
        }
    }
    const float invl = 1.f / l_i;
#pragma unroll
    for (int vt = 0; vt < 4; vt++) {
        bf16x4 o;
#pragma unroll
        for (int r = 0; r < 4; r++) o[r] = (bf16)(acc[vt][r] * invl);
        *(bf16x4*)(ctx + (size_t)(b * Tz + qt + q16) * 1024 + h * 64 + vt * 16 + quad * 4) = o;
    }
}

// ---------------- driver ----------------
extern "C" void kernel_launch(void* const* d_in, const int* in_sizes, int n_in,
                              void* d_out, int out_size, void* d_ws, size_t ws_size,
                              hipStream_t stream)
{
    const float* x     = (const float*)d_in[0];
    const float* w_q   = (const float*)d_in[1];
    const float* w_k   = (const float*)d_in[2];
    const float* w_v   = (const float*)d_in[3];
    const float* w_o   = (const float*)d_in[4];
    const float* b_o   = (const float*)d_in[5];
    const float* w_fc1 = (const float*)d_in[6];
    const float* b_fc1 = (const float*)d_in[7];
    const float* w_fc2 = (const float*)d_in[8];
    const float* b_fc2 = (const float*)d_in[9];
    const float* ln1_g = (const float*)d_in[10];
    const float* ln1_b = (const float*)d_in[11];
    const float* ln2_g = (const float*)d_in[12];
    const float* ln2_b = (const float*)d_in[13];
    float* out = (float*)d_out;

    char* p = (char*)d_ws;
    bf16* wqkvT = (bf16*)p; p += (size_t)3072 * 1024 * 2;
    bf16* woT   = (bf16*)p; p += (size_t)1024 * 1024 * 2;
    bf16* wfc1T = (bf16*)p; p += (size_t)4096 * 1024 * 2;
    bf16* wfc2T = (bf16*)p; p += (size_t)1024 * 4096 * 2;
    bf16* h1    = (bf16*)p; p += (size_t)NR * 1024 * 2;
    bf16* qkv   = (bf16*)p; p += (size_t)NR * 3072 * 2;
    bf16* ctx   = (bf16*)p; p += (size_t)NR * 1024 * 2;
    float* y    = (float*)p; p += (size_t)NR * 1024 * 4;
    bf16* h2    = (bf16*)p; p += (size_t)NR * 1024 * 2;
    bf16* g     = (bf16*)p; p += (size_t)NR * 4096 * 2;

    const dim3 tb(32, 8);
    k_transpose_cvt<<<dim3(32, 32),  tb, 0, stream>>>(w_q,   wqkvT,              1024, 1024);
    k_transpose_cvt<<<dim3(32, 32),  tb, 0, stream>>>(w_k,   wqkvT + 1024*1024,  1024, 1024);
    k_transpose_cvt<<<dim3(32, 32),  tb, 0, stream>>>(w_v,   wqkvT + 2048*1024,  1024, 1024);
    k_transpose_cvt<<<dim3(32, 32),  tb, 0, stream>>>(w_o,   woT,                1024, 1024);
    k_transpose_cvt<<<dim3(128, 32), tb, 0, stream>>>(w_fc1, wfc1T,              1024, 4096);
    k_transpose_cvt<<<dim3(32, 128), tb, 0, stream>>>(w_fc2, wfc2T,              4096, 1024);

    k_layernorm<<<NR, 256, 0, stream>>>(x, ln1_g, ln1_b, h1);
    k_gemm<<<dim3(3072/128, NR/128), 256, 0, stream>>>(h1, wqkvT, NR, 3072, 1024,
                                                       nullptr, nullptr, nullptr, qkv, 0);
    k_attn<<<dim3(Tz/64, Hz, Bz), 256, 0, stream>>>(qkv, ctx);
    k_gemm<<<dim3(1024/128, NR/128), 256, 0, stream>>>(ctx, woT, NR, 1024, 1024,
                                                       b_o, x, y, nullptr, 0);
    k_layernorm<<<NR, 256, 0, stream>>>(y, ln2_g, ln2_b, h2);
    k_gemm<<<dim3(4096/128, NR/128), 256, 0, stream>>>(h2, wfc1T, NR, 4096, 1024,
                                                       b_fc1, nullptr, nullptr, g, 1);
    k_gemm<<<dim3(1024/128, NR/128), 256, 0, stream>>>(g, wfc2T, NR, 1024, 4096,
                                                       b_fc2, y, out, nullptr, 0);
    (void)in_sizes; (void)n_in; (void)out_size; (void)ws_size;
}

// Round 2
// 570.081 us; speedup vs baseline: 1.0034x; 1.0034x over previous
//
#include <hip/hip_runtime.h>
#include <hip/hip_bf16.h>
#include <cstdint>

#define Bz 2
#define Tz 2048
#define Dz 1024
#define Hz 16
#define NR (Bz*Tz)   // 4096 rows

typedef __bf16 bf16;
typedef __bf16 bf16x8 __attribute__((ext_vector_type(8)));
typedef __bf16 bf16x4 __attribute__((ext_vector_type(4)));
typedef short  s16x4  __attribute__((ext_vector_type(4)));
typedef float  f32x4  __attribute__((ext_vector_type(4)));

typedef unsigned int u32as1 __attribute__((address_space(1)));
typedef unsigned int u32as3 __attribute__((address_space(3)));

__device__ __forceinline__ void gl2lds16(const void* gp, void* lp) {
    __builtin_amdgcn_global_load_lds((u32as1*)gp, (u32as3*)lp, 16, 0, 0);
}

// ---------------- transpose + f32->bf16 cast (+scale): W[K][N] -> WT[N][K] ----------------
__global__ void k_transpose_cvt(const float* __restrict__ W, bf16* __restrict__ WT,
                                int K, int N, float scale) {
    __shared__ float tile[32][33];
    const int n0 = blockIdx.x * 32, k0 = blockIdx.y * 32;
    const int tx = threadIdx.x, ty = threadIdx.y;   // (32,8)
#pragma unroll
    for (int i = 0; i < 4; i++)
        tile[ty + i*8][tx] = W[(size_t)(k0 + ty + i*8) * N + n0 + tx];
    __syncthreads();
#pragma unroll
    for (int i = 0; i < 4; i++)
        WT[(size_t)(n0 + ty + i*8) * K + k0 + tx] = (bf16)(tile[tx][ty + i*8] * scale);
}

// ---------------- V transpose: qkv V-third -> Vt[(b*16+h)*64 + v][Tz] ----------------
__global__ void k_vtrans(const bf16* __restrict__ qkv, bf16* __restrict__ Vt) {
    __shared__ bf16 tile[64][72];   // [t_local][v], padded
    const int t0 = blockIdx.x * 64;
    const int bh = blockIdx.y;
    const int b = bh >> 4, h = bh & 15;
    const int tid = threadIdx.x;
    const int tr = tid >> 3, c8 = (tid & 7) * 8;
    const bf16* src = qkv + (size_t)b * Tz * 3072 + 2048 + h * 64;
#pragma unroll
    for (int i = 0; i < 2; i++) {
        bf16x8 v = *(const bf16x8*)(src + (size_t)(t0 + i*32 + tr) * 3072 + c8);
        *(bf16x8*)&tile[i*32 + tr][c8] = v;
    }
    __syncthreads();
    bf16* dst = Vt + (size_t)bh * 64 * Tz + t0;
#pragma unroll
    for (int i = 0; i < 2; i++) {
        const int vr = i*32 + tr;
        bf16x8 o;
#pragma unroll
        for (int j = 0; j < 8; j++) o[j] = tile[c8 + j][vr];
        *(bf16x8*)(dst + (size_t)vr * Tz + c8) = o;
    }
}

// ---------------- LayerNorm (ddof=1 std, eps added to std) -> bf16 ----------------
__global__ void k_layernorm(const float* __restrict__ X, const float* __restrict__ gam,
                            const float* __restrict__ bet, bf16* __restrict__ out) {
    const int row = blockIdx.x, t = threadIdx.x;   // 256 threads, D=1024
    const float4 v = ((const float4*)(X + (size_t)row * Dz))[t];
    float s  = v.x + v.y + v.z + v.w;
    float ss = v.x*v.x + v.y*v.y + v.z*v.z + v.w*v.w;
#pragma unroll
    for (int o = 1; o < 64; o <<= 1) { s += __shfl_xor(s, o); ss += __shfl_xor(ss, o); }
    __shared__ float rs[4], rss[4];
    if ((t & 63) == 0) { rs[t >> 6] = s; rss[t >> 6] = ss; }
    __syncthreads();
    s  = rs[0] + rs[1] + rs[2] + rs[3];
    ss = rss[0] + rss[1] + rss[2] + rss[3];
    const float mean = s * (1.f / Dz);
    const float var  = fmaxf((ss - s * mean) * (1.f / (Dz - 1)), 0.f);
    const float inv  = 1.f / (sqrtf(var) + 1e-6f);
    const float4 gv = ((const float4*)gam)[t];
    const float4 bv = ((const float4*)bet)[t];
    bf16x4 o;
    o[0] = (bf16)((v.x - mean) * gv.x * inv + bv.x);
    o[1] = (bf16)((v.y - mean) * gv.y * inv + bv.y);
    o[2] = (bf16)((v.z - mean) * gv.z * inv + bv.z);
    o[3] = (bf16)((v.w - mean) * gv.w * inv + bv.w);
    *(bf16x4*)(out + (size_t)row * Dz + t * 4) = o;
}

// ---------------- generic bf16 GEMM: C[M][N] = A[M][K] * BT[N][K]^T ----------------
__global__ __launch_bounds__(256) void k_gemm(
    const bf16* __restrict__ A, const bf16* __restrict__ BT,
    int M, int N, int K,
    const float* __restrict__ bias, const float* __restrict__ resid,
    float* __restrict__ Cf, bf16* __restrict__ Cb, int act)
{
    __shared__ bf16 lA[128 * 64];
    __shared__ bf16 lB[128 * 64];
    const int tid = threadIdx.x;
    const int w = tid >> 6, lane = tid & 63;
    const int q = lane >> 4, l16 = lane & 15;
    const int m0 = blockIdx.y * 128, n0 = blockIdx.x * 128;
    const int wm = (w >> 1) * 64, wn = (w & 1) * 64;

    const int srow = lane >> 3;                 // 0..7
    const int skg  = (lane & 7) ^ srow;         // XOR-swizzled k-slot
    const bf16* Ab = A  + (size_t)(m0 + w * 32 + srow) * K + skg * 8;
    const bf16* Bb = BT + (size_t)(n0 + w * 32 + srow) * K + skg * 8;
    bf16* lAw = lA + w * 2048;
    bf16* lBw = lB + w * 2048;

    f32x4 acc[4][4] = {};

    for (int k0 = 0; k0 < K; k0 += 64) {
#pragma unroll
        for (int i = 0; i < 4; i++) {
            gl2lds16(Ab + (size_t)i * 8 * K + k0, lAw + i * 512);
            gl2lds16(Bb + (size_t)i * 8 * K + k0, lBw + i * 512);
        }
        __syncthreads();
#pragma unroll
        for (int kh = 0; kh < 2; kh++) {
            const int sl = (((kh * 4 + q) ^ (l16 & 7)) * 8);
            bf16x8 af[4], bfr[4];
#pragma unroll
            for (int t = 0; t < 4; t++) {
                af[t]  = *(const bf16x8*)(lA + (wm + t * 16 + l16) * 64 + sl);
                bfr[t] = *(const bf16x8*)(lB + (wn + t * 16 + l16) * 64 + sl);
            }
#pragma unroll
            for (int i = 0; i < 4; i++)
#pragma unroll
                for (int j = 0; j < 4; j++)
                    acc[i][j] = __builtin_amdgcn_mfma_f32_16x16x32_bf16(
                        af[i], bfr[j], acc[i][j], 0, 0, 0);
        }
        __syncthreads();
    }

#pragma unroll
    for (int i = 0; i < 4; i++) {
        const int gr = m0 + wm + i * 16 + q * 4;
#pragma unroll
        for (int j = 0; j < 4; j++) {
            const int gc = n0 + wn + j * 16 + l16;
            const float bv = bias ? bias[gc] : 0.f;
#pragma unroll
            for (int r = 0; r < 4; r++) {
                float v = acc[i][j][r] + bv;
                if (act) v = 0.5f * v * (1.f + erff(v * 0.70710678118f));
                const size_t idx = (size_t)(gr + r) * N + gc;
                if (resid) v += resid[idx];
                if (Cf) Cf[idx] = v;
                else    Cb[idx] = (bf16)v;
            }
        }
    }
}

// ---------------- flash attention v2: 64-key tiles, 32q/wave, split-K wave pairs ----------------
// Scale 1/sqrt(dk) pre-folded into w_q. qkv: [NR][3072] (q|k|v). Vt: [(b*16+h)*64+v][Tz].
// Wave (wq,ws): q rows [qb*64+wq*32, +32), key tiles kt = (2i+ws)*64. Merge via LDS.
__global__ __launch_bounds__(256) void k_attn(const bf16* __restrict__ qkv,
                                              const bf16* __restrict__ Vt,
                                              bf16* __restrict__ ctx)
{
    __shared__ f32x4 sAcc[2][2][4][64];   // [wq][g][vt][lane] from ws=1
    __shared__ float sM[2][2][64], sL[2][2][64];

    const int tid = threadIdx.x, lane = tid & 63;
    const int l16 = lane & 15, quad = lane >> 4;
    const int w = tid >> 6;
    const int wq = w & 1, ws = w >> 1;
    const int qb = gridDim.x - 1 - blockIdx.x;           // heavy blocks first
    const int h = blockIdx.y, b = blockIdx.z;
    const int q0 = qb * 64 + wq * 32;

    const bf16* Qp  = qkv + (size_t)b * Tz * 3072 + h * 64;
    const bf16* Kp  = Qp + 1024;
    const bf16* Vtp = Vt + (size_t)(b * Hz + h) * 64 * Tz;

    bf16x8 qf[2][2];
#pragma unroll
    for (int g = 0; g < 2; g++)
#pragma unroll
        for (int kh = 0; kh < 2; kh++)
            qf[g][kh] = *(const bf16x8*)(Qp + (size_t)(q0 + g*16 + l16) * 3072 + kh*32 + quad*8);

    f32x4 acc[2][4] = {};
    float m[2] = {-1e30f, -1e30f}, l[2] = {0.f, 0.f};

    for (int kt = ws * 64; kt < q0 + 32; kt += 128) {
        // S^T = K*Q^T : 16 mfma_16x16x32 for 2 groups
        f32x4 sv[2][4];
#pragma unroll
        for (int c = 0; c < 4; c++) {
            bf16x8 kf0 = *(const bf16x8*)(Kp + (size_t)(kt + c*16 + l16) * 3072 + quad*8);
            bf16x8 kf1 = *(const bf16x8*)(Kp + (size_t)(kt + c*16 + l16) * 3072 + 32 + quad*8);
#pragma unroll
            for (int g = 0; g < 2; g++) {
                f32x4 z = {0.f, 0.f, 0.f, 0.f};
                z = __builtin_amdgcn_mfma_f32_16x16x32_bf16(kf0, qf[g][0], z, 0, 0, 0);
                z = __builtin_amdgcn_mfma_f32_16x16x32_bf16(kf1, qf[g][1], z, 0, 0, 0);
                sv[g][c] = z;
            }
        }
        // V^T fragments (contiguous bf16x4 loads), shared by both q-groups
        s16x4 vf[4][4];
#pragma unroll
        for (int c = 0; c < 4; c++)
#pragma unroll
            for (int vt = 0; vt < 4; vt++)
                vf[c][vt] = *(const s16x4*)(Vtp + (size_t)(vt*16 + l16) * Tz + kt + c*16 + quad*4);

        // causal mask (tail tiles only; wave-uniform branch)
        if (kt + 63 > q0) {
#pragma unroll
            for (int g = 0; g < 2; g++)
#pragma unroll
                for (int c = 0; c < 4; c++)
#pragma unroll
                    for (int r = 0; r < 4; r++)
                        if (kt + c*16 + quad*4 + r > q0 + g*16 + l16) sv[g][c][r] = -1e30f;
        }
        // online softmax
        float tm[2];
#pragma unroll
        for (int g = 0; g < 2; g++) {
            float t0 = fmaxf(fmaxf(sv[g][0][0], sv[g][0][1]), fmaxf(sv[g][0][2], sv[g][0][3]));
            float t1 = fmaxf(fmaxf(sv[g][1][0], sv[g][1][1]), fmaxf(sv[g][1][2], sv[g][1][3]));
            float t2 = fmaxf(fmaxf(sv[g][2][0], sv[g][2][1]), fmaxf(sv[g][2][2], sv[g][2][3]));
            float t3 = fmaxf(fmaxf(sv[g][3][0], sv[g][3][1]), fmaxf(sv[g][3][2], sv[g][3][3]));
            float t4 = fmaxf(fmaxf(t0, t1), fmaxf(t2, t3));
            t4 = fmaxf(t4, __shfl_xor(t4, 16));
            t4 = fmaxf(t4, __shfl_xor(t4, 32));
            tm[g] = t4;
        }
        if (__any((tm[0] > m[0]) || (tm[1] > m[1]))) {
#pragma unroll
            for (int g = 0; g < 2; g++) {
                const float mn = fmaxf(m[g], tm[g]);
                const float a  = __expf(m[g] - mn);
                m[g] = mn;
                l[g] *= a;
#pragma unroll
                for (int vt = 0; vt < 4; vt++)
#pragma unroll
                    for (int r = 0; r < 4; r++) acc[g][vt][r] *= a;
            }
        }
        s16x4 pb[2][4];
        float ts[2] = {0.f, 0.f};
#pragma unroll
        for (int g = 0; g < 2; g++) {
#pragma unroll
            for (int c = 0; c < 4; c++) {
                bf16x4 t;
#pragma unroll
                for (int r = 0; r < 4; r++) {
                    const float p = __expf(sv[g][c][r] - m[g]);
                    ts[g] += p;
                    t[r] = (bf16)p;
                }
                pb[g][c] = __builtin_bit_cast(s16x4, t);
            }
            float s2 = ts[g];
            s2 += __shfl_xor(s2, 16);
            s2 += __shfl_xor(s2, 32);
            l[g] += s2;
        }
        // PV: O^T += V^T * P^T  (16x16x16_1k, V-frags reused across groups)
#pragma unroll
        for (int c = 0; c < 4; c++)
#pragma unroll
            for (int g = 0; g < 2; g++)
#pragma unroll
                for (int vt = 0; vt < 4; vt++)
                    acc[g][vt] = __builtin_amdgcn_mfma_f32_16x16x16bf16_1k(
                        vf[c][vt], pb[g][c], acc[g][vt], 0, 0, 0);
    }

    // merge split-K halves
    if (ws == 1) {
#pragma unroll
        for (int g = 0; g < 2; g++) {
            sM[wq][g][lane] = m[g];
            sL[wq][g][lane] = l[g];
#pragma unroll
            for (int vt = 0; vt < 4; vt++) sAcc[wq][g][vt][lane] = acc[g][vt];
        }
    }
    __syncthreads();
    if (ws == 0) {
#pragma unroll
        for (int g = 0; g < 2; g++) {
            const float m1 = sM[wq][g][lane], l1 = sL[wq][g][lane];
            const float M  = fmaxf(m[g], m1);
            const float a0 = __expf(m[g] - M), a1 = __expf(m1 - M);
            const float inv = 1.f / (l[g] * a0 + l1 * a1);
#pragma unroll
            for (int vt = 0; vt < 4; vt++) {
                const f32x4 o1 = sAcc[wq][g][vt][lane];
                bf16x4 o;
#pragma unroll
                for (int r = 0; r < 4; r++)
                    o[r] = (bf16)((acc[g][vt][r] * a0 + o1[r] * a1) * inv);
                *(bf16x4*)(ctx + (size_t)(b * Tz + q0 + g*16 + l16) * 1024
                           + h * 64 + vt * 16 + quad * 4) = o;
            }
        }
    }
}

// ---------------- driver ----------------
extern "C" void kernel_launch(void* const* d_in, const int* in_sizes, int n_in,
                              void* d_out, int out_size, void* d_ws, size_t ws_size,
                              hipStream_t stream)
{
    const float* x     = (const float*)d_in[0];
    const float* w_q   = (const float*)d_in[1];
    const float* w_k   = (const float*)d_in[2];
    const float* w_v   = (const float*)d_in[3];
    const float* w_o   = (const float*)d_in[4];
    const float* b_o   = (const float*)d_in[5];
    const float* w_fc1 = (const float*)d_in[6];
    const float* b_fc1 = (const float*)d_in[7];
    const float* w_fc2 = (const float*)d_in[8];
    const float* b_fc2 = (const float*)d_in[9];
    const float* ln1_g = (const float*)d_in[10];
    const float* ln1_b = (const float*)d_in[11];
    const float* ln2_g = (const float*)d_in[12];
    const float* ln2_b = (const float*)d_in[13];
    float* out = (float*)d_out;

    char* p = (char*)d_ws;
    bf16* wqkvT = (bf16*)p; p += (size_t)3072 * 1024 * 2;
    bf16* woT   = (bf16*)p; p += (size_t)1024 * 1024 * 2;
    bf16* wfc1T = (bf16*)p; p += (size_t)4096 * 1024 * 2;
    bf16* wfc2T = (bf16*)p; p += (size_t)1024 * 4096 * 2;
    bf16* h1    = (bf16*)p; p += (size_t)NR * 1024 * 2;   // reused as Vt after QKV GEMM
    bf16* qkv   = (bf16*)p; p += (size_t)NR * 3072 * 2;
    bf16* ctx   = (bf16*)p; p += (size_t)NR * 1024 * 2;
    float* y    = (float*)p; p += (size_t)NR * 1024 * 4;
    bf16* h2    = (bf16*)p; p += (size_t)NR * 1024 * 2;
    bf16* g     = (bf16*)p; p += (size_t)NR * 4096 * 2;
    bf16* Vt    = h1;   // [ (b*16+h)*64 + v ][ Tz ]  (8.4 MB, same size as h1)

    const dim3 tb(32, 8);
    k_transpose_cvt<<<dim3(32, 32),  tb, 0, stream>>>(w_q,   wqkvT,             1024, 1024, 0.125f);
    k_transpose_cvt<<<dim3(32, 32),  tb, 0, stream>>>(w_k,   wqkvT + 1024*1024, 1024, 1024, 1.f);
    k_transpose_cvt<<<dim3(32, 32),  tb, 0, stream>>>(w_v,   wqkvT + 2048*1024, 1024, 1024, 1.f);
    k_transpose_cvt<<<dim3(32, 32),  tb, 0, stream>>>(w_o,   woT,               1024, 1024, 1.f);
    k_transpose_cvt<<<dim3(128, 32), tb, 0, stream>>>(w_fc1, wfc1T,             1024, 4096, 1.f);
    k_transpose_cvt<<<dim3(32, 128), tb, 0, stream>>>(w_fc2, wfc2T,             4096, 1024, 1.f);

    k_layernorm<<<NR, 256, 0, stream>>>(x, ln1_g, ln1_b, h1);
    k_gemm<<<dim3(3072/128, NR/128), 256, 0, stream>>>(h1, wqkvT, NR, 3072, 1024,
                                                       nullptr, nullptr, nullptr, qkv, 0);
    k_vtrans<<<dim3(Tz/64, Bz*Hz), 256, 0, stream>>>(qkv, Vt);
    k_attn<<<dim3(Tz/64, Hz, Bz), 256, 0, stream>>>(qkv, Vt, ctx);
    k_gemm<<<dim3(1024/128, NR/128), 256, 0, stream>>>(ctx, woT, NR, 1024, 1024,
                                                       b_o, x, y, nullptr, 0);
    k_layernorm<<<NR, 256, 0, stream>>>(y, ln2_g, ln2_b, h2);
    k_gemm<<<dim3(4096/128, NR/128), 256, 0, stream>>>(h2, wfc1T, NR, 4096, 1024,
                                                       b_fc1, nullptr, nullptr, g, 1);
    k_gemm<<<dim3(1024/128, NR/128), 256, 0, stream>>>(g, wfc2T, NR, 1024, 4096,
                                                       b_fc2, y, out, nullptr, 0);
    (void)in_sizes; (void)n_in; (void)out_size; (void)ws_size;
}

// Round 3
// 472.821 us; speedup vs baseline: 1.2098x; 1.2057x over previous
//
#include <hip/hip_runtime.h>
#include <hip/hip_bf16.h>
#include <cstdint>

#define Bz 2
#define Tz 2048
#define Dz 1024
#define Hz 16
#define NR (Bz*Tz)   // 4096 rows

typedef __bf16 bf16;
typedef __bf16 bf16x8 __attribute__((ext_vector_type(8)));
typedef __bf16 bf16x4 __attribute__((ext_vector_type(4)));
typedef short  s16x4  __attribute__((ext_vector_type(4)));
typedef float  f32x4  __attribute__((ext_vector_type(4)));

typedef unsigned int u32as1 __attribute__((address_space(1)));
typedef unsigned int u32as3 __attribute__((address_space(3)));

__device__ __forceinline__ void gl2lds16(const void* gp, void* lp) {
    __builtin_amdgcn_global_load_lds((u32as1*)gp, (u32as3*)lp, 16, 0, 0);
}

// ---------------- transpose + f32->bf16 cast (+scale): W[K][N] -> WT[N][K] ----------------
__global__ void k_transpose_cvt(const float* __restrict__ W, bf16* __restrict__ WT,
                                int K, int N, float scale) {
    __shared__ float tile[32][33];
    const int n0 = blockIdx.x * 32, k0 = blockIdx.y * 32;
    const int tx = threadIdx.x, ty = threadIdx.y;   // (32,8)
#pragma unroll
    for (int i = 0; i < 4; i++)
        tile[ty + i*8][tx] = W[(size_t)(k0 + ty + i*8) * N + n0 + tx];
    __syncthreads();
#pragma unroll
    for (int i = 0; i < 4; i++)
        WT[(size_t)(n0 + ty + i*8) * K + k0 + tx] = (bf16)(tile[tx][ty + i*8] * scale);
}

// ---------------- V transpose: qkv V-third -> Vt[(b*16+h)*64 + v][Tz] ----------------
__global__ void k_vtrans(const bf16* __restrict__ qkv, bf16* __restrict__ Vt) {
    __shared__ bf16 tile[64][72];   // [t_local][v], padded
    const int t0 = blockIdx.x * 64;
    const int bh = blockIdx.y;
    const int b = bh >> 4, h = bh & 15;
    const int tid = threadIdx.x;
    const int tr = tid >> 3, c8 = (tid & 7) * 8;
    const bf16* src = qkv + (size_t)b * Tz * 3072 + 2048 + h * 64;
#pragma unroll
    for (int i = 0; i < 2; i++) {
        bf16x8 v = *(const bf16x8*)(src + (size_t)(t0 + i*32 + tr) * 3072 + c8);
        *(bf16x8*)&tile[i*32 + tr][c8] = v;
    }
    __syncthreads();
    bf16* dst = Vt + (size_t)bh * 64 * Tz + t0;
#pragma unroll
    for (int i = 0; i < 2; i++) {
        const int vr = i*32 + tr;
        bf16x8 o;
#pragma unroll
        for (int j = 0; j < 8; j++) o[j] = tile[c8 + j][vr];
        *(bf16x8*)(dst + (size_t)vr * Tz + c8) = o;
    }
}

// ---------------- LayerNorm (ddof=1 std, eps added to std) -> bf16 ----------------
__global__ void k_layernorm(const float* __restrict__ X, const float* __restrict__ gam,
                            const float* __restrict__ bet, bf16* __restrict__ out) {
    const int row = blockIdx.x, t = threadIdx.x;   // 256 threads, D=1024
    const float4 v = ((const float4*)(X + (size_t)row * Dz))[t];
    float s  = v.x + v.y + v.z + v.w;
    float ss = v.x*v.x + v.y*v.y + v.z*v.z + v.w*v.w;
#pragma unroll
    for (int o = 1; o < 64; o <<= 1) { s += __shfl_xor(s, o); ss += __shfl_xor(ss, o); }
    __shared__ float rs[4], rss[4];
    if ((t & 63) == 0) { rs[t >> 6] = s; rss[t >> 6] = ss; }
    __syncthreads();
    s  = rs[0] + rs[1] + rs[2] + rs[3];
    ss = rss[0] + rss[1] + rss[2] + rss[3];
    const float mean = s * (1.f / Dz);
    const float var  = fmaxf((ss - s * mean) * (1.f / (Dz - 1)), 0.f);
    const float inv  = 1.f / (sqrtf(var) + 1e-6f);
    const float4 gv = ((const float4*)gam)[t];
    const float4 bv = ((const float4*)bet)[t];
    bf16x4 o;
    o[0] = (bf16)((v.x - mean) * gv.x * inv + bv.x);
    o[1] = (bf16)((v.y - mean) * gv.y * inv + bv.y);
    o[2] = (bf16)((v.z - mean) * gv.z * inv + bv.z);
    o[3] = (bf16)((v.w - mean) * gv.w * inv + bv.w);
    *(bf16x4*)(out + (size_t)row * Dz + t * 4) = o;
}

// ---------------- generic bf16 GEMM: C[M][N] = A[M][K] * BT[N][K]^T ----------------
__global__ __launch_bounds__(256) void k_gemm(
    const bf16* __restrict__ A, const bf16* __restrict__ BT,
    int M, int N, int K,
    const float* __restrict__ bias, const float* __restrict__ resid,
    float* __restrict__ Cf, bf16* __restrict__ Cb, int act)
{
    __shared__ bf16 lA[128 * 64];
    __shared__ bf16 lB[128 * 64];
    const int tid = threadIdx.x;
    const int w = tid >> 6, lane = tid & 63;
    const int q = lane >> 4, l16 = lane & 15;
    const int m0 = blockIdx.y * 128, n0 = blockIdx.x * 128;
    const int wm = (w >> 1) * 64, wn = (w & 1) * 64;

    const int srow = lane >> 3;                 // 0..7
    const int skg  = (lane & 7) ^ srow;         // XOR-swizzled k-slot
    const bf16* Ab = A  + (size_t)(m0 + w * 32 + srow) * K + skg * 8;
    const bf16* Bb = BT + (size_t)(n0 + w * 32 + srow) * K + skg * 8;
    bf16* lAw = lA + w * 2048;
    bf16* lBw = lB + w * 2048;

    f32x4 acc[4][4] = {};

    for (int k0 = 0; k0 < K; k0 += 64) {
#pragma unroll
        for (int i = 0; i < 4; i++) {
            gl2lds16(Ab + (size_t)i * 8 * K + k0, lAw + i * 512);
            gl2lds16(Bb + (size_t)i * 8 * K + k0, lBw + i * 512);
        }
        __syncthreads();
#pragma unroll
        for (int kh = 0; kh < 2; kh++) {
            const int sl = (((kh * 4 + q) ^ (l16 & 7)) * 8);
            bf16x8 af[4], bfr[4];
#pragma unroll
            for (int t = 0; t < 4; t++) {
                af[t]  = *(const bf16x8*)(lA + (wm + t * 16 + l16) * 64 + sl);
                bfr[t] = *(const bf16x8*)(lB + (wn + t * 16 + l16) * 64 + sl);
            }
#pragma unroll
            for (int i = 0; i < 4; i++)
#pragma unroll
                for (int j = 0; j < 4; j++)
                    acc[i][j] = __builtin_amdgcn_mfma_f32_16x16x32_bf16(
                        af[i], bfr[j], acc[i][j], 0, 0, 0);
        }
        __syncthreads();
    }

#pragma unroll
    for (int i = 0; i < 4; i++) {
        const int gr = m0 + wm + i * 16 + q * 4;
#pragma unroll
        for (int j = 0; j < 4; j++) {
            const int gc = n0 + wn + j * 16 + l16;
            const float bv = bias ? bias[gc] : 0.f;
#pragma unroll
            for (int r = 0; r < 4; r++) {
                float v = acc[i][j][r] + bv;
                if (act) v = 0.5f * v * (1.f + erff(v * 0.70710678118f));
                const size_t idx = (size_t)(gr + r) * N + gc;
                if (resid) v += resid[idx];
                if (Cf) Cf[idx] = v;
                else    Cb[idx] = (bf16)v;
            }
        }
    }
}

// ---------------- flash attention v3: block-cooperative LDS staging ----------------
// Grid (Tz/64, Hz, Bz). Block = 64 q rows; waves (wq,ws): wq picks 32 q rows,
// ws splits keys (even/odd 64-key tiles). Per 128-key iter the BLOCK stages
// K[128][64] (16KB) + V^T[64][128] (16KB) into LDS via global_load_lds16 with
// XOR slot swizzle; all waves read frags from LDS. Merge aliases staging LDS.
__global__ __launch_bounds__(256) void k_attn(const bf16* __restrict__ qkv,
                                              const bf16* __restrict__ Vt,
                                              bf16* __restrict__ ctx)
{
    __shared__ __align__(16) char smem[34816];
    bf16* lK = (bf16*)smem;             // [128 rows][64 elems], row = 128B = 8 slots
    bf16* lV = (bf16*)(smem + 16384);   // [64 rows][128 elems], row = 256B = 16 slots
    f32x4* sAcc = (f32x4*)smem;                 // [wq][g][vt][lane] (aliases lK)
    float*  sM  = (float*)(smem + 32768);       // [wq][g][lane]
    float*  sL  = (float*)(smem + 33792);

    const int tid = threadIdx.x, lane = tid & 63, w = tid >> 6;
    const int l16 = lane & 15, quad = lane >> 4;
    const int wq = w & 1, ws = w >> 1;
    const int qb = gridDim.x - 1 - blockIdx.x;   // heavy blocks first
    const int h = blockIdx.y, b = blockIdx.z;
    const int q0 = qb * 64 + wq * 32;

    const bf16* Qp  = qkv + (size_t)b * Tz * 3072 + h * 64;
    const bf16* Kp  = Qp + 1024;
    const bf16* Vtp = Vt + (size_t)(b * Hz + h) * 64 * Tz;

    // thread-constant staging addresses (shot s adds s*32 K-rows / s*16 V-rows)
    const int krow  = tid >> 3;                    // K local row 0..31
    const int kslot = (tid & 7) ^ (krow & 7);      // swizzled 16B slot
    const bf16* Kg = Kp + (size_t)krow * 3072 + kslot * 8;
    const int vrow  = tid >> 4;                    // V local row 0..15
    const int vslot = (tid & 15) ^ (vrow & 7);
    const bf16* Vg = Vtp + (size_t)vrow * Tz + vslot * 8;

    bf16x8 qf[2][2];
#pragma unroll
    for (int g = 0; g < 2; g++)
#pragma unroll
        for (int kh = 0; kh < 2; kh++)
            qf[g][kh] = *(const bf16x8*)(Qp + (size_t)(q0 + g*16 + l16) * 3072 + kh*32 + quad*8);

    f32x4 acc[2][4] = {};
    float m[2] = {-1e30f, -1e30f}, l[2] = {0.f, 0.f};

    const int keyEnd = qb * 64 + 64;
    for (int ktB = 0; ktB < keyEnd; ktB += 128) {
        if (ktB) __syncthreads();
#pragma unroll
        for (int s = 0; s < 4; s++) {
            gl2lds16(Kg + (size_t)(ktB + s * 32) * 3072, lK + s * 2048 + w * 512);
            gl2lds16(Vg + (size_t)s * 16 * Tz + ktB,     lV + s * 2048 + w * 512);
        }
        __syncthreads();

        const int kt = ktB + ws * 64;
        if (kt <= q0 + 31) {                      // wave-uniform
            // S^T = K*Q^T from LDS K frags
            f32x4 sv[2][4];
            const int sw = l16 & 7;
#pragma unroll
            for (int c = 0; c < 4; c++) {
                const int R = ws * 64 + c * 16 + l16;
                bf16x8 kf0 = *(const bf16x8*)(lK + R * 64 + ((quad     ^ sw) * 8));
                bf16x8 kf1 = *(const bf16x8*)(lK + R * 64 + (((4+quad) ^ sw) * 8));
#pragma unroll
                for (int g = 0; g < 2; g++) {
                    f32x4 z = {0.f, 0.f, 0.f, 0.f};
                    z = __builtin_amdgcn_mfma_f32_16x16x32_bf16(kf0, qf[g][0], z, 0, 0, 0);
                    z = __builtin_amdgcn_mfma_f32_16x16x32_bf16(kf1, qf[g][1], z, 0, 0, 0);
                    sv[g][c] = z;
                }
            }
            // causal mask (tail tiles only)
            if (kt + 63 > q0) {
#pragma unroll
                for (int g = 0; g < 2; g++)
#pragma unroll
                    for (int c = 0; c < 4; c++)
#pragma unroll
                        for (int r = 0; r < 4; r++)
                            if (kt + c*16 + quad*4 + r > q0 + g*16 + l16) sv[g][c][r] = -1e30f;
            }
            // online softmax
            float tm[2];
#pragma unroll
            for (int g = 0; g < 2; g++) {
                float t0 = fmaxf(fmaxf(sv[g][0][0], sv[g][0][1]), fmaxf(sv[g][0][2], sv[g][0][3]));
                float t1 = fmaxf(fmaxf(sv[g][1][0], sv[g][1][1]), fmaxf(sv[g][1][2], sv[g][1][3]));
                float t2 = fmaxf(fmaxf(sv[g][2][0], sv[g][2][1]), fmaxf(sv[g][2][2], sv[g][2][3]));
                float t3 = fmaxf(fmaxf(sv[g][3][0], sv[g][3][1]), fmaxf(sv[g][3][2], sv[g][3][3]));
                float t4 = fmaxf(fmaxf(t0, t1), fmaxf(t2, t3));
                t4 = fmaxf(t4, __shfl_xor(t4, 16));
                t4 = fmaxf(t4, __shfl_xor(t4, 32));
                tm[g] = t4;
            }
            if (__any((tm[0] > m[0]) || (tm[1] > m[1]))) {
#pragma unroll
                for (int g = 0; g < 2; g++) {
                    const float mn = fmaxf(m[g], tm[g]);
                    const float a  = __expf(m[g] - mn);
                    m[g] = mn;
                    l[g] *= a;
#pragma unroll
                    for (int vt = 0; vt < 4; vt++)
#pragma unroll
                        for (int r = 0; r < 4; r++) acc[g][vt][r] *= a;
                }
            }
            // P build + PV, V frags from LDS (shared across g)
            float ts0 = 0.f, ts1 = 0.f;
#pragma unroll
            for (int c = 0; c < 4; c++) {
                s16x4 vf[4];
                const int gslot = ws * 8 + c * 2 + (quad >> 1);
#pragma unroll
                for (int vt = 0; vt < 4; vt++) {
                    const int Rv = vt * 16 + l16;
                    vf[vt] = *(const s16x4*)(lV + Rv * 128 + ((gslot ^ (Rv & 7)) * 8)
                                             + (quad & 1) * 4);
                }
#pragma unroll
                for (int g = 0; g < 2; g++) {
                    bf16x4 t;
#pragma unroll
                    for (int r = 0; r < 4; r++) {
                        const float p = __expf(sv[g][c][r] - m[g]);
                        if (g == 0) ts0 += p; else ts1 += p;
                        t[r] = (bf16)p;
                    }
                    const s16x4 pb = __builtin_bit_cast(s16x4, t);
#pragma unroll
                    for (int vt = 0; vt < 4; vt++)
                        acc[g][vt] = __builtin_amdgcn_mfma_f32_16x16x16bf16_1k(
                            vf[vt], pb, acc[g][vt], 0, 0, 0);
                }
            }
            ts0 += __shfl_xor(ts0, 16); ts0 += __shfl_xor(ts0, 32);
            ts1 += __shfl_xor(ts1, 16); ts1 += __shfl_xor(ts1, 32);
            l[0] += ts0; l[1] += ts1;
        }
    }

    // merge split-K halves (LDS aliased onto staging buffers)
    __syncthreads();
    if (ws == 1) {
#pragma unroll
        for (int g = 0; g < 2; g++) {
            sM[(wq*2 + g) * 64 + lane] = m[g];
            sL[(wq*2 + g) * 64 + lane] = l[g];
#pragma unroll
            for (int vt = 0; vt < 4; vt++)
                sAcc[((wq*2 + g) * 4 + vt) * 64 + lane] = acc[g][vt];
        }
    }
    __syncthreads();
    if (ws == 0) {
#pragma unroll
        for (int g = 0; g < 2; g++) {
            const float m1 = sM[(wq*2 + g) * 64 + lane], l1 = sL[(wq*2 + g) * 64 + lane];
            const float M  = fmaxf(m[g], m1);
            const float a0 = __expf(m[g] - M), a1 = __expf(m1 - M);
            const float inv = 1.f / (l[g] * a0 + l1 * a1);
#pragma unroll
            for (int vt = 0; vt < 4; vt++) {
                const f32x4 o1 = sAcc[((wq*2 + g) * 4 + vt) * 64 + lane];
                bf16x4 o;
#pragma unroll
                for (int r = 0; r < 4; r++)
                    o[r] = (bf16)((acc[g][vt][r] * a0 + o1[r] * a1) * inv);
                *(bf16x4*)(ctx + (size_t)(b * Tz + q0 + g*16 + l16) * 1024
                           + h * 64 + vt * 16 + quad * 4) = o;
            }
        }
    }
}

// ---------------- driver ----------------
extern "C" void kernel_launch(void* const* d_in, const int* in_sizes, int n_in,
                              void* d_out, int out_size, void* d_ws, size_t ws_size,
                              hipStream_t stream)
{
    const float* x     = (const float*)d_in[0];
    const float* w_q   = (const float*)d_in[1];
    const float* w_k   = (const float*)d_in[2];
    const float* w_v   = (const float*)d_in[3];
    const float* w_o   = (const float*)d_in[4];
    const float* b_o   = (const float*)d_in[5];
    const float* w_fc1 = (const float*)d_in[6];
    const float* b_fc1 = (const float*)d_in[7];
    const float* w_fc2 = (const float*)d_in[8];
    const float* b_fc2 = (const float*)d_in[9];
    const float* ln1_g = (const float*)d_in[10];
    const float* ln1_b = (const float*)d_in[11];
    const float* ln2_g = (const float*)d_in[12];
    const float* ln2_b = (const float*)d_in[13];
    float* out = (float*)d_out;

    char* p = (char*)d_ws;
    bf16* wqkvT = (bf16*)p; p += (size_t)3072 * 1024 * 2;
    bf16* woT   = (bf16*)p; p += (size_t)1024 * 1024 * 2;
    bf16* wfc1T = (bf16*)p; p += (size_t)4096 * 1024 * 2;
    bf16* wfc2T = (bf16*)p; p += (size_t)1024 * 4096 * 2;
    bf16* h1    = (bf16*)p; p += (size_t)NR * 1024 * 2;   // reused as Vt after QKV GEMM
    bf16* qkv   = (bf16*)p; p += (size_t)NR * 3072 * 2;
    bf16* ctx   = (bf16*)p; p += (size_t)NR * 1024 * 2;
    float* y    = (float*)p; p += (size_t)NR * 1024 * 4;
    bf16* h2    = (bf16*)p; p += (size_t)NR * 1024 * 2;
    bf16* g     = (bf16*)p; p += (size_t)NR * 4096 * 2;
    bf16* Vt    = h1;   // [ (b*16+h)*64 + v ][ Tz ]

    const dim3 tb(32, 8);
    k_transpose_cvt<<<dim3(32, 32),  tb, 0, stream>>>(w_q,   wqkvT,             1024, 1024, 0.125f);
    k_transpose_cvt<<<dim3(32, 32),  tb, 0, stream>>>(w_k,   wqkvT + 1024*1024, 1024, 1024, 1.f);
    k_transpose_cvt<<<dim3(32, 32),  tb, 0, stream>>>(w_v,   wqkvT + 2048*1024, 1024, 1024, 1.f);
    k_transpose_cvt<<<dim3(32, 32),  tb, 0, stream>>>(w_o,   woT,               1024, 1024, 1.f);
    k_transpose_cvt<<<dim3(128, 32), tb, 0, stream>>>(w_fc1, wfc1T,             1024, 4096, 1.f);
    k_transpose_cvt<<<dim3(32, 128), tb, 0, stream>>>(w_fc2, wfc2T,             4096, 1024, 1.f);

    k_layernorm<<<NR, 256, 0, stream>>>(x, ln1_g, ln1_b, h1);
    k_gemm<<<dim3(3072/128, NR/128), 256, 0, stream>>>(h1, wqkvT, NR, 3072, 1024,
                                                       nullptr, nullptr, nullptr, qkv, 0);
    k_vtrans<<<dim3(Tz/64, Bz*Hz), 256, 0, stream>>>(qkv, Vt);
    k_attn<<<dim3(Tz/64, Hz, Bz), 256, 0, stream>>>(qkv, Vt, ctx);
    k_gemm<<<dim3(1024/128, NR/128), 256, 0, stream>>>(ctx, woT, NR, 1024, 1024,
                                                       b_o, x, y, nullptr, 0);
    k_layernorm<<<NR, 256, 0, stream>>>(y, ln2_g, ln2_b, h2);
    k_gemm<<<dim3(4096/128, NR/128), 256, 0, stream>>>(h2, wfc1T, NR, 4096, 1024,
                                                       b_fc1, nullptr, nullptr, g, 1);
    k_gemm<<<dim3(1024/128, NR/128), 256, 0, stream>>>(g, wfc2T, NR, 1024, 4096,
                                                       b_fc2, y, out, nullptr, 0);
    (void)in_sizes; (void)n_in; (void)out_size; (void)ws_size;
}

// Round 4
// 428.876 us; speedup vs baseline: 1.3337x; 1.1025x over previous
//
#include <hip/hip_runtime.h>
#include <hip/hip_bf16.h>
#include <cstdint>

#define Bz 2
#define Tz 2048
#define Dz 1024
#define Hz 16
#define NR (Bz*Tz)   // 4096 rows

typedef __bf16 bf16;
typedef __bf16 bf16x8 __attribute__((ext_vector_type(8)));
typedef __bf16 bf16x4 __attribute__((ext_vector_type(4)));
typedef short  s16x4  __attribute__((ext_vector_type(4)));
typedef float  f32x4  __attribute__((ext_vector_type(4)));

typedef unsigned int u32as1 __attribute__((address_space(1)));
typedef unsigned int u32as3 __attribute__((address_space(3)));

__device__ __forceinline__ void gl2lds16(const void* gp, void* lp) {
    __builtin_amdgcn_global_load_lds((u32as1*)gp, (u32as3*)lp, 16, 0, 0);
}

// ---------------- transpose + f32->bf16 cast (+scale): W[K][N] -> WT[N][K] ----------------
__global__ void k_transpose_cvt(const float* __restrict__ W, bf16* __restrict__ WT,
                                int K, int N, float scale) {
    __shared__ float tile[32][33];
    const int n0 = blockIdx.x * 32, k0 = blockIdx.y * 32;
    const int tx = threadIdx.x, ty = threadIdx.y;   // (32,8)
#pragma unroll
    for (int i = 0; i < 4; i++)
        tile[ty + i*8][tx] = W[(size_t)(k0 + ty + i*8) * N + n0 + tx];
    __syncthreads();
#pragma unroll
    for (int i = 0; i < 4; i++)
        WT[(size_t)(n0 + ty + i*8) * K + k0 + tx] = (bf16)(tile[tx][ty + i*8] * scale);
}

// ---------------- V transpose: qkv V-third -> Vt[(b*16+h)*64 + v][Tz] ----------------
__global__ void k_vtrans(const bf16* __restrict__ qkv, bf16* __restrict__ Vt) {
    __shared__ bf16 tile[64][72];   // [t_local][v], padded
    const int t0 = blockIdx.x * 64;
    const int bh = blockIdx.y;
    const int b = bh >> 4, h = bh & 15;
    const int tid = threadIdx.x;
    const int tr = tid >> 3, c8 = (tid & 7) * 8;
    const bf16* src = qkv + (size_t)b * Tz * 3072 + 2048 + h * 64;
#pragma unroll
    for (int i = 0; i < 2; i++) {
        bf16x8 v = *(const bf16x8*)(src + (size_t)(t0 + i*32 + tr) * 3072 + c8);
        *(bf16x8*)&tile[i*32 + tr][c8] = v;
    }
    __syncthreads();
    bf16* dst = Vt + (size_t)bh * 64 * Tz + t0;
#pragma unroll
    for (int i = 0; i < 2; i++) {
        const int vr = i*32 + tr;
        bf16x8 o;
#pragma unroll
        for (int j = 0; j < 8; j++) o[j] = tile[c8 + j][vr];
        *(bf16x8*)(dst + (size_t)vr * Tz + c8) = o;
    }
}

// ---------------- LayerNorm (ddof=1 std, eps added to std) -> bf16 ----------------
__global__ void k_layernorm(const float* __restrict__ X, const float* __restrict__ gam,
                            const float* __restrict__ bet, bf16* __restrict__ out) {
    const int row = blockIdx.x, t = threadIdx.x;   // 256 threads, D=1024
    const float4 v = ((const float4*)(X + (size_t)row * Dz))[t];
    float s  = v.x + v.y + v.z + v.w;
    float ss = v.x*v.x + v.y*v.y + v.z*v.z + v.w*v.w;
#pragma unroll
    for (int o = 1; o < 64; o <<= 1) { s += __shfl_xor(s, o); ss += __shfl_xor(ss, o); }
    __shared__ float rs[4], rss[4];
    if ((t & 63) == 0) { rs[t >> 6] = s; rss[t >> 6] = ss; }
    __syncthreads();
    s  = rs[0] + rs[1] + rs[2] + rs[3];
    ss = rss[0] + rss[1] + rss[2] + rss[3];
    const float mean = s * (1.f / Dz);
    const float var  = fmaxf((ss - s * mean) * (1.f / (Dz - 1)), 0.f);
    const float inv  = 1.f / (sqrtf(var) + 1e-6f);
    const float4 gv = ((const float4*)gam)[t];
    const float4 bv = ((const float4*)bet)[t];
    bf16x4 o;
    o[0] = (bf16)((v.x - mean) * gv.x * inv + bv.x);
    o[1] = (bf16)((v.y - mean) * gv.y * inv + bv.y);
    o[2] = (bf16)((v.z - mean) * gv.z * inv + bv.z);
    o[3] = (bf16)((v.w - mean) * gv.w * inv + bv.w);
    *(bf16x4*)(out + (size_t)row * Dz + t * 4) = o;
}

// ---------------- generic bf16 GEMM: C[M][N] = A[M][K] * BT[N][K]^T ----------------
// 128x128 tile, BK=64. Optional split-K: gridDim.z = nsplit, each z computes a
// K-slice and writes raw f32 partials to Cpart[z][M][N] (reduced by k_reduce).
__global__ __launch_bounds__(256) void k_gemm(
    const bf16* __restrict__ A, const bf16* __restrict__ BT,
    int M, int N, int K,
    const float* __restrict__ bias, const float* __restrict__ resid,
    float* __restrict__ Cf, bf16* __restrict__ Cb, int act,
    float* __restrict__ Cpart, int nsplit)
{
    __shared__ bf16 lA[128 * 64];
    __shared__ bf16 lB[128 * 64];
    const int tid = threadIdx.x;
    const int w = tid >> 6, lane = tid & 63;
    const int q = lane >> 4, l16 = lane & 15;
    const int m0 = blockIdx.y * 128, n0 = blockIdx.x * 128;
    const int wm = (w >> 1) * 64, wn = (w & 1) * 64;

    const int srow = lane >> 3;                 // 0..7
    const int skg  = (lane & 7) ^ srow;         // XOR-swizzled k-slot
    const bf16* Ab = A  + (size_t)(m0 + w * 32 + srow) * K + skg * 8;
    const bf16* Bb = BT + (size_t)(n0 + w * 32 + srow) * K + skg * 8;
    bf16* lAw = lA + w * 2048;
    bf16* lBw = lB + w * 2048;

    f32x4 acc[4][4] = {};

    const int kPer = K / nsplit;
    const int kBeg = blockIdx.z * kPer, kEnd = kBeg + kPer;
    for (int k0 = kBeg; k0 < kEnd; k0 += 64) {
#pragma unroll
        for (int i = 0; i < 4; i++) {
            gl2lds16(Ab + (size_t)i * 8 * K + k0, lAw + i * 512);
            gl2lds16(Bb + (size_t)i * 8 * K + k0, lBw + i * 512);
        }
        __syncthreads();
#pragma unroll
        for (int kh = 0; kh < 2; kh++) {
            const int sl = (((kh * 4 + q) ^ (l16 & 7)) * 8);
            bf16x8 af[4], bfr[4];
#pragma unroll
            for (int t = 0; t < 4; t++) {
                af[t]  = *(const bf16x8*)(lA + (wm + t * 16 + l16) * 64 + sl);
                bfr[t] = *(const bf16x8*)(lB + (wn + t * 16 + l16) * 64 + sl);
            }
#pragma unroll
            for (int i = 0; i < 4; i++)
#pragma unroll
                for (int j = 0; j < 4; j++)
                    acc[i][j] = __builtin_amdgcn_mfma_f32_16x16x32_bf16(
                        af[i], bfr[j], acc[i][j], 0, 0, 0);
        }
        __syncthreads();
    }

    if (nsplit > 1) {
        float* P = Cpart + (size_t)blockIdx.z * M * N;
#pragma unroll
        for (int i = 0; i < 4; i++) {
            const int gr = m0 + wm + i * 16 + q * 4;
#pragma unroll
            for (int j = 0; j < 4; j++) {
                const int gc = n0 + wn + j * 16 + l16;
#pragma unroll
                for (int r = 0; r < 4; r++)
                    P[(size_t)(gr + r) * N + gc] = acc[i][j][r];
            }
        }
        return;
    }

#pragma unroll
    for (int i = 0; i < 4; i++) {
        const int gr = m0 + wm + i * 16 + q * 4;
#pragma unroll
        for (int j = 0; j < 4; j++) {
            const int gc = n0 + wn + j * 16 + l16;
            const float bv = bias ? bias[gc] : 0.f;
#pragma unroll
            for (int r = 0; r < 4; r++) {
                float v = acc[i][j][r] + bv;
                if (act) v = 0.5f * v * (1.f + erff(v * 0.70710678118f));
                const size_t idx = (size_t)(gr + r) * N + gc;
                if (resid) v += resid[idx];
                if (Cf) Cf[idx] = v;
                else    Cb[idx] = (bf16)v;
            }
        }
    }
}

// ---------------- split-K reduce + epilogue (bias/act/resid, f32 or bf16 out) ----------------
__global__ __launch_bounds__(256) void k_reduce(
    const float* __restrict__ part, int nsplit, size_t MN, int N,
    const float* __restrict__ bias, const float* __restrict__ resid,
    float* __restrict__ Cf, bf16* __restrict__ Cb, int act)
{
    const size_t i4 = ((size_t)blockIdx.x * 256 + threadIdx.x) * 4;
    float4 v = *(const float4*)(part + i4);
    for (int s = 1; s < nsplit; s++) {
        const float4 p = *(const float4*)(part + s * MN + i4);
        v.x += p.x; v.y += p.y; v.z += p.z; v.w += p.w;
    }
    const int col = (int)(i4 % N);
    if (bias) {
        const float4 bv = *(const float4*)(bias + col);
        v.x += bv.x; v.y += bv.y; v.z += bv.z; v.w += bv.w;
    }
    if (act) {
        v.x = 0.5f * v.x * (1.f + erff(v.x * 0.70710678118f));
        v.y = 0.5f * v.y * (1.f + erff(v.y * 0.70710678118f));
        v.z = 0.5f * v.z * (1.f + erff(v.z * 0.70710678118f));
        v.w = 0.5f * v.w * (1.f + erff(v.w * 0.70710678118f));
    }
    if (resid) {
        const float4 rv = *(const float4*)(resid + i4);
        v.x += rv.x; v.y += rv.y; v.z += rv.z; v.w += rv.w;
    }
    if (Cf) *(float4*)(Cf + i4) = v;
    else {
        bf16x4 o; o[0] = (bf16)v.x; o[1] = (bf16)v.y; o[2] = (bf16)v.z; o[3] = (bf16)v.w;
        *(bf16x4*)(Cb + i4) = o;
    }
}

// ---------------- flash attention v3: block-cooperative LDS staging ----------------
__global__ __launch_bounds__(256) void k_attn(const bf16* __restrict__ qkv,
                                              const bf16* __restrict__ Vt,
                                              bf16* __restrict__ ctx)
{
    __shared__ __align__(16) char smem[34816];
    bf16* lK = (bf16*)smem;             // [128 rows][64 elems]
    bf16* lV = (bf16*)(smem + 16384);   // [64 rows][128 elems]
    f32x4* sAcc = (f32x4*)smem;
    float*  sM  = (float*)(smem + 32768);
    float*  sL  = (float*)(smem + 33792);

    const int tid = threadIdx.x, lane = tid & 63, w = tid >> 6;
    const int l16 = lane & 15, quad = lane >> 4;
    const int wq = w & 1, ws = w >> 1;
    const int qb = gridDim.x - 1 - blockIdx.x;   // heavy blocks first
    const int h = blockIdx.y, b = blockIdx.z;
    const int q0 = qb * 64 + wq * 32;

    const bf16* Qp  = qkv + (size_t)b * Tz * 3072 + h * 64;
    const bf16* Kp  = Qp + 1024;
    const bf16* Vtp = Vt + (size_t)(b * Hz + h) * 64 * Tz;

    const int krow  = tid >> 3;
    const int kslot = (tid & 7) ^ (krow & 7);
    const bf16* Kg = Kp + (size_t)krow * 3072 + kslot * 8;
    const int vrow  = tid >> 4;
    const int vslot = (tid & 15) ^ (vrow & 7);
    const bf16* Vg = Vtp + (size_t)vrow * Tz + vslot * 8;

    bf16x8 qf[2][2];
#pragma unroll
    for (int g = 0; g < 2; g++)
#pragma unroll
        for (int kh = 0; kh < 2; kh++)
            qf[g][kh] = *(const bf16x8*)(Qp + (size_t)(q0 + g*16 + l16) * 3072 + kh*32 + quad*8);

    f32x4 acc[2][4] = {};
    float m[2] = {-1e30f, -1e30f}, l[2] = {0.f, 0.f};

    const int keyEnd = qb * 64 + 64;
    for (int ktB = 0; ktB < keyEnd; ktB += 128) {
        if (ktB) __syncthreads();
#pragma unroll
        for (int s = 0; s < 4; s++) {
            gl2lds16(Kg + (size_t)(ktB + s * 32) * 3072, lK + s * 2048 + w * 512);
            gl2lds16(Vg + (size_t)s * 16 * Tz + ktB,     lV + s * 2048 + w * 512);
        }
        __syncthreads();

        const int kt = ktB + ws * 64;
        if (kt <= q0 + 31) {                      // wave-uniform
            f32x4 sv[2][4];
            const int sw = l16 & 7;
#pragma unroll
            for (int c = 0; c < 4; c++) {
                const int R = ws * 64 + c * 16 + l16;
                bf16x8 kf0 = *(const bf16x8*)(lK + R * 64 + ((quad     ^ sw) * 8));
                bf16x8 kf1 = *(const bf16x8*)(lK + R * 64 + (((4+quad) ^ sw) * 8));
#pragma unroll
                for (int g = 0; g < 2; g++) {
                    f32x4 z = {0.f, 0.f, 0.f, 0.f};
                    z = __builtin_amdgcn_mfma_f32_16x16x32_bf16(kf0, qf[g][0], z, 0, 0, 0);
                    z = __builtin_amdgcn_mfma_f32_16x16x32_bf16(kf1, qf[g][1], z, 0, 0, 0);
                    sv[g][c] = z;
                }
            }
            if (kt + 63 > q0) {
#pragma unroll
                for (int g = 0; g < 2; g++)
#pragma unroll
                    for (int c = 0; c < 4; c++)
#pragma unroll
                        for (int r = 0; r < 4; r++)
                            if (kt + c*16 + quad*4 + r > q0 + g*16 + l16) sv[g][c][r] = -1e30f;
            }
            float tm[2];
#pragma unroll
            for (int g = 0; g < 2; g++) {
                float t0 = fmaxf(fmaxf(sv[g][0][0], sv[g][0][1]), fmaxf(sv[g][0][2], sv[g][0][3]));
                float t1 = fmaxf(fmaxf(sv[g][1][0], sv[g][1][1]), fmaxf(sv[g][1][2], sv[g][1][3]));
                float t2 = fmaxf(fmaxf(sv[g][2][0], sv[g][2][1]), fmaxf(sv[g][2][2], sv[g][2][3]));
                float t3 = fmaxf(fmaxf(sv[g][3][0], sv[g][3][1]), fmaxf(sv[g][3][2], sv[g][3][3]));
                float t4 = fmaxf(fmaxf(t0, t1), fmaxf(t2, t3));
                t4 = fmaxf(t4, __shfl_xor(t4, 16));
                t4 = fmaxf(t4, __shfl_xor(t4, 32));
                tm[g] = t4;
            }
            if (__any((tm[0] > m[0]) || (tm[1] > m[1]))) {
#pragma unroll
                for (int g = 0; g < 2; g++) {
                    const float mn = fmaxf(m[g], tm[g]);
                    const float a  = __expf(m[g] - mn);
                    m[g] = mn;
                    l[g] *= a;
#pragma unroll
                    for (int vt = 0; vt < 4; vt++)
#pragma unroll
                        for (int r = 0; r < 4; r++) acc[g][vt][r] *= a;
                }
            }
            float ts0 = 0.f, ts1 = 0.f;
#pragma unroll
            for (int c = 0; c < 4; c++) {
                s16x4 vf[4];
                const int gslot = ws * 8 + c * 2 + (quad >> 1);
#pragma unroll
                for (int vt = 0; vt < 4; vt++) {
                    const int Rv = vt * 16 + l16;
                    vf[vt] = *(const s16x4*)(lV + Rv * 128 + ((gslot ^ (Rv & 7)) * 8)
                                             + (quad & 1) * 4);
                }
#pragma unroll
                for (int g = 0; g < 2; g++) {
                    bf16x4 t;
#pragma unroll
                    for (int r = 0; r < 4; r++) {
                        const float p = __expf(sv[g][c][r] - m[g]);
                        if (g == 0) ts0 += p; else ts1 += p;
                        t[r] = (bf16)p;
                    }
                    const s16x4 pb = __builtin_bit_cast(s16x4, t);
#pragma unroll
                    for (int vt = 0; vt < 4; vt++)
                        acc[g][vt] = __builtin_amdgcn_mfma_f32_16x16x16bf16_1k(
                            vf[vt], pb, acc[g][vt], 0, 0, 0);
                }
            }
            ts0 += __shfl_xor(ts0, 16); ts0 += __shfl_xor(ts0, 32);
            ts1 += __shfl_xor(ts1, 16); ts1 += __shfl_xor(ts1, 32);
            l[0] += ts0; l[1] += ts1;
        }
    }

    __syncthreads();
    if (ws == 1) {
#pragma unroll
        for (int g = 0; g < 2; g++) {
            sM[(wq*2 + g) * 64 + lane] = m[g];
            sL[(wq*2 + g) * 64 + lane] = l[g];
#pragma unroll
            for (int vt = 0; vt < 4; vt++)
                sAcc[((wq*2 + g) * 4 + vt) * 64 + lane] = acc[g][vt];
        }
    }
    __syncthreads();
    if (ws == 0) {
#pragma unroll
        for (int g = 0; g < 2; g++) {
            const float m1 = sM[(wq*2 + g) * 64 + lane], l1 = sL[(wq*2 + g) * 64 + lane];
            const float M  = fmaxf(m[g], m1);
            const float a0 = __expf(m[g] - M), a1 = __expf(m1 - M);
            const float inv = 1.f / (l[g] * a0 + l1 * a1);
#pragma unroll
            for (int vt = 0; vt < 4; vt++) {
                const f32x4 o1 = sAcc[((wq*2 + g) * 4 + vt) * 64 + lane];
                bf16x4 o;
#pragma unroll
                for (int r = 0; r < 4; r++)
                    o[r] = (bf16)((acc[g][vt][r] * a0 + o1[r] * a1) * inv);
                *(bf16x4*)(ctx + (size_t)(b * Tz + q0 + g*16 + l16) * 1024
                           + h * 64 + vt * 16 + quad * 4) = o;
            }
        }
    }
}

// ---------------- driver ----------------
extern "C" void kernel_launch(void* const* d_in, const int* in_sizes, int n_in,
                              void* d_out, int out_size, void* d_ws, size_t ws_size,
                              hipStream_t stream)
{
    const float* x     = (const float*)d_in[0];
    const float* w_q   = (const float*)d_in[1];
    const float* w_k   = (const float*)d_in[2];
    const float* w_v   = (const float*)d_in[3];
    const float* w_o   = (const float*)d_in[4];
    const float* b_o   = (const float*)d_in[5];
    const float* w_fc1 = (const float*)d_in[6];
    const float* b_fc1 = (const float*)d_in[7];
    const float* w_fc2 = (const float*)d_in[8];
    const float* b_fc2 = (const float*)d_in[9];
    const float* ln1_g = (const float*)d_in[10];
    const float* ln1_b = (const float*)d_in[11];
    const float* ln2_g = (const float*)d_in[12];
    const float* ln2_b = (const float*)d_in[13];
    float* out = (float*)d_out;

    char* p = (char*)d_ws;
    bf16* wqkvT = (bf16*)p; p += (size_t)3072 * 1024 * 2;
    bf16* woT   = (bf16*)p; p += (size_t)1024 * 1024 * 2;
    bf16* wfc1T = (bf16*)p; p += (size_t)4096 * 1024 * 2;
    bf16* wfc2T = (bf16*)p; p += (size_t)1024 * 4096 * 2;
    bf16* h1    = (bf16*)p; p += (size_t)NR * 1024 * 2;   // reused: Vt, then FC2 partials
    bf16* qkv   = (bf16*)p; p += (size_t)NR * 3072 * 2;   // FC2 partials tail
    bf16* ctx   = (bf16*)p; p += (size_t)NR * 1024 * 2;
    float* y    = (float*)p; p += (size_t)NR * 1024 * 4;
    bf16* h2    = (bf16*)p; p += (size_t)NR * 1024 * 2;
    bf16* g     = (bf16*)p; p += (size_t)NR * 4096 * 2;   // reused: proj partials
    bf16* Vt    = h1;
    float* projPart = (float*)g;    // 2 * 4096*1024*4 B = 33.55 MB == sizeof(g)
    float* fc2Part  = (float*)h1;   // 33.55 MB == sizeof(h1)+sizeof(qkv)

    const dim3 tb(32, 8);
    k_transpose_cvt<<<dim3(32, 32),  tb, 0, stream>>>(w_q,   wqkvT,             1024, 1024, 0.125f);
    k_transpose_cvt<<<dim3(32, 32),  tb, 0, stream>>>(w_k,   wqkvT + 1024*1024, 1024, 1024, 1.f);
    k_transpose_cvt<<<dim3(32, 32),  tb, 0, stream>>>(w_v,   wqkvT + 2048*1024, 1024, 1024, 1.f);
    k_transpose_cvt<<<dim3(32, 32),  tb, 0, stream>>>(w_o,   woT,               1024, 1024, 1.f);
    k_transpose_cvt<<<dim3(128, 32), tb, 0, stream>>>(w_fc1, wfc1T,             1024, 4096, 1.f);
    k_transpose_cvt<<<dim3(32, 128), tb, 0, stream>>>(w_fc2, wfc2T,             4096, 1024, 1.f);

    k_layernorm<<<NR, 256, 0, stream>>>(x, ln1_g, ln1_b, h1);
    k_gemm<<<dim3(3072/128, NR/128), 256, 0, stream>>>(h1, wqkvT, NR, 3072, 1024,
                                                       nullptr, nullptr, nullptr, qkv, 0,
                                                       nullptr, 1);
    k_vtrans<<<dim3(Tz/64, Bz*Hz), 256, 0, stream>>>(qkv, Vt);
    k_attn<<<dim3(Tz/64, Hz, Bz), 256, 0, stream>>>(qkv, Vt, ctx);

    // out-proj: split-K=2 -> partials in g, reduce fuses +b_o +x -> y (f32)
    k_gemm<<<dim3(1024/128, NR/128, 2), 256, 0, stream>>>(ctx, woT, NR, 1024, 1024,
                                                          nullptr, nullptr, nullptr, nullptr, 0,
                                                          projPart, 2);
    k_reduce<<<(size_t)NR * 1024 / 1024, 256, 0, stream>>>(projPart, 2, (size_t)NR * 1024, 1024,
                                                           b_o, x, y, nullptr, 0);

    k_layernorm<<<NR, 256, 0, stream>>>(y, ln2_g, ln2_b, h2);
    k_gemm<<<dim3(4096/128, NR/128), 256, 0, stream>>>(h2, wfc1T, NR, 4096, 1024,
                                                       b_fc1, nullptr, nullptr, g, 1,
                                                       nullptr, 1);
    // FC2: split-K=2 -> partials in h1+qkv, reduce fuses +b_fc2 +y -> out (f32)
    k_gemm<<<dim3(1024/128, NR/128, 2), 256, 0, stream>>>(g, wfc2T, NR, 1024, 4096,
                                                          nullptr, nullptr, nullptr, nullptr, 0,
                                                          fc2Part, 2);
    k_reduce<<<(size_t)NR * 1024 / 1024, 256, 0, stream>>>(fc2Part, 2, (size_t)NR * 1024, 1024,
                                                           b_fc2, y, out, nullptr, 0);
    (void)in_sizes; (void)n_in; (void)out_size; (void)ws_size;
}

// Round 5
// 424.065 us; speedup vs baseline: 1.3489x; 1.0113x over previous
//
#include <hip/hip_runtime.h>
#include <hip/hip_bf16.h>
#include <cstdint>

#define Bz 2
#define Tz 2048
#define Dz 1024
#define Hz 16
#define NR (Bz*Tz)   // 4096 rows

typedef __bf16 bf16;
typedef __bf16 bf16x8 __attribute__((ext_vector_type(8)));
typedef __bf16 bf16x4 __attribute__((ext_vector_type(4)));
typedef short  s16x4  __attribute__((ext_vector_type(4)));
typedef float  f32x4  __attribute__((ext_vector_type(4)));

typedef unsigned int u32as1 __attribute__((address_space(1)));
typedef unsigned int u32as3 __attribute__((address_space(3)));

__device__ __forceinline__ void gl2lds16(const void* gp, void* lp) {
    __builtin_amdgcn_global_load_lds((u32as1*)gp, (u32as3*)lp, 16, 0, 0);
}

// ---------------- transpose + f32->bf16 cast (+scale): W[K][N] -> WT[N][K] ----------------
__global__ void k_transpose_cvt(const float* __restrict__ W, bf16* __restrict__ WT,
                                int K, int N, float scale) {
    __shared__ float tile[32][33];
    const int n0 = blockIdx.x * 32, k0 = blockIdx.y * 32;
    const int tx = threadIdx.x, ty = threadIdx.y;   // (32,8)
#pragma unroll
    for (int i = 0; i < 4; i++)
        tile[ty + i*8][tx] = W[(size_t)(k0 + ty + i*8) * N + n0 + tx];
    __syncthreads();
#pragma unroll
    for (int i = 0; i < 4; i++)
        WT[(size_t)(n0 + ty + i*8) * K + k0 + tx] = (bf16)(tile[tx][ty + i*8] * scale);
}

// ---------------- V transpose: qkv V-third -> Vt[(b*16+h)*64 + v][Tz] ----------------
__global__ void k_vtrans(const bf16* __restrict__ qkv, bf16* __restrict__ Vt) {
    __shared__ bf16 tile[64][72];   // [t_local][v], padded
    const int t0 = blockIdx.x * 64;
    const int bh = blockIdx.y;
    const int b = bh >> 4, h = bh & 15;
    const int tid = threadIdx.x;
    const int tr = tid >> 3, c8 = (tid & 7) * 8;
    const bf16* src = qkv + (size_t)b * Tz * 3072 + 2048 + h * 64;
#pragma unroll
    for (int i = 0; i < 2; i++) {
        bf16x8 v = *(const bf16x8*)(src + (size_t)(t0 + i*32 + tr) * 3072 + c8);
        *(bf16x8*)&tile[i*32 + tr][c8] = v;
    }
    __syncthreads();
    bf16* dst = Vt + (size_t)bh * 64 * Tz + t0;
#pragma unroll
    for (int i = 0; i < 2; i++) {
        const int vr = i*32 + tr;
        bf16x8 o;
#pragma unroll
        for (int j = 0; j < 8; j++) o[j] = tile[c8 + j][vr];
        *(bf16x8*)(dst + (size_t)vr * Tz + c8) = o;
    }
}

// ---------------- LayerNorm (ddof=1 std, eps added to std) -> bf16 ----------------
__global__ void k_layernorm(const float* __restrict__ X, const float* __restrict__ gam,
                            const float* __restrict__ bet, bf16* __restrict__ out) {
    const int row = blockIdx.x, t = threadIdx.x;   // 256 threads, D=1024
    const float4 v = ((const float4*)(X + (size_t)row * Dz))[t];
    float s  = v.x + v.y + v.z + v.w;
    float ss = v.x*v.x + v.y*v.y + v.z*v.z + v.w*v.w;
#pragma unroll
    for (int o = 1; o < 64; o <<= 1) { s += __shfl_xor(s, o); ss += __shfl_xor(ss, o); }
    __shared__ float rs[4], rss[4];
    if ((t & 63) == 0) { rs[t >> 6] = s; rss[t >> 6] = ss; }
    __syncthreads();
    s  = rs[0] + rs[1] + rs[2] + rs[3];
    ss = rss[0] + rss[1] + rss[2] + rss[3];
    const float mean = s * (1.f / Dz);
    const float var  = fmaxf((ss - s * mean) * (1.f / (Dz - 1)), 0.f);
    const float inv  = 1.f / (sqrtf(var) + 1e-6f);
    const float4 gv = ((const float4*)gam)[t];
    const float4 bv = ((const float4*)bet)[t];
    bf16x4 o;
    o[0] = (bf16)((v.x - mean) * gv.x * inv + bv.x);
    o[1] = (bf16)((v.y - mean) * gv.y * inv + bv.y);
    o[2] = (bf16)((v.z - mean) * gv.z * inv + bv.z);
    o[3] = (bf16)((v.w - mean) * gv.w * inv + bv.w);
    *(bf16x4*)(out + (size_t)row * Dz + t * 4) = o;
}

// ---------------- generic bf16 GEMM: C[M][N] = A[M][K] * BT[N][K]^T ----------------
// 128x128 tile, BK=64. Optional split-K: gridDim.z = nsplit, each z computes a
// K-slice and writes raw f32 partials to Cpart[z][M][N] (reduced by k_reduce).
__global__ __launch_bounds__(256) void k_gemm(
    const bf16* __restrict__ A, const bf16* __restrict__ BT,
    int M, int N, int K,
    const float* __restrict__ bias, const float* __restrict__ resid,
    float* __restrict__ Cf, bf16* __restrict__ Cb, int act,
    float* __restrict__ Cpart, int nsplit)
{
    __shared__ bf16 lA[128 * 64];
    __shared__ bf16 lB[128 * 64];
    const int tid = threadIdx.x;
    const int w = tid >> 6, lane = tid & 63;
    const int q = lane >> 4, l16 = lane & 15;
    const int m0 = blockIdx.y * 128, n0 = blockIdx.x * 128;
    const int wm = (w >> 1) * 64, wn = (w & 1) * 64;

    const int srow = lane >> 3;                 // 0..7
    const int skg  = (lane & 7) ^ srow;         // XOR-swizzled k-slot
    const bf16* Ab = A  + (size_t)(m0 + w * 32 + srow) * K + skg * 8;
    const bf16* Bb = BT + (size_t)(n0 + w * 32 + srow) * K + skg * 8;
    bf16* lAw = lA + w * 2048;
    bf16* lBw = lB + w * 2048;

    f32x4 acc[4][4] = {};

    const int kPer = K / nsplit;
    const int kBeg = blockIdx.z * kPer, kEnd = kBeg + kPer;
    for (int k0 = kBeg; k0 < kEnd; k0 += 64) {
#pragma unroll
        for (int i = 0; i < 4; i++) {
            gl2lds16(Ab + (size_t)i * 8 * K + k0, lAw + i * 512);
            gl2lds16(Bb + (size_t)i * 8 * K + k0, lBw + i * 512);
        }
        __syncthreads();
#pragma unroll
        for (int kh = 0; kh < 2; kh++) {
            const int sl = (((kh * 4 + q) ^ (l16 & 7)) * 8);
            bf16x8 af[4], bfr[4];
#pragma unroll
            for (int t = 0; t < 4; t++) {
                af[t]  = *(const bf16x8*)(lA + (wm + t * 16 + l16) * 64 + sl);
                bfr[t] = *(const bf16x8*)(lB + (wn + t * 16 + l16) * 64 + sl);
            }
#pragma unroll
            for (int i = 0; i < 4; i++)
#pragma unroll
                for (int j = 0; j < 4; j++)
                    acc[i][j] = __builtin_amdgcn_mfma_f32_16x16x32_bf16(
                        af[i], bfr[j], acc[i][j], 0, 0, 0);
        }
        __syncthreads();
    }

    if (nsplit > 1) {
        float* P = Cpart + (size_t)blockIdx.z * M * N;
#pragma unroll
        for (int i = 0; i < 4; i++) {
            const int gr = m0 + wm + i * 16 + q * 4;
#pragma unroll
            for (int j = 0; j < 4; j++) {
                const int gc = n0 + wn + j * 16 + l16;
#pragma unroll
                for (int r = 0; r < 4; r++)
                    P[(size_t)(gr + r) * N + gc] = acc[i][j][r];
            }
        }
        return;
    }

#pragma unroll
    for (int i = 0; i < 4; i++) {
        const int gr = m0 + wm + i * 16 + q * 4;
#pragma unroll
        for (int j = 0; j < 4; j++) {
            const int gc = n0 + wn + j * 16 + l16;
            const float bv = bias ? bias[gc] : 0.f;
#pragma unroll
            for (int r = 0; r < 4; r++) {
                float v = acc[i][j][r] + bv;
                if (act) v = 0.5f * v * (1.f + erff(v * 0.70710678118f));
                const size_t idx = (size_t)(gr + r) * N + gc;
                if (resid) v += resid[idx];
                if (Cf) Cf[idx] = v;
                else    Cb[idx] = (bf16)v;
            }
        }
    }
}

// ---------------- split-K reduce + epilogue (bias/act/resid, f32 or bf16 out) ----------------
__global__ __launch_bounds__(256) void k_reduce(
    const float* __restrict__ part, int nsplit, size_t MN, int N,
    const float* __restrict__ bias, const float* __restrict__ resid,
    float* __restrict__ Cf, bf16* __restrict__ Cb, int act)
{
    const size_t i4 = ((size_t)blockIdx.x * 256 + threadIdx.x) * 4;
    float4 v = *(const float4*)(part + i4);
    for (int s = 1; s < nsplit; s++) {
        const float4 p = *(const float4*)(part + s * MN + i4);
        v.x += p.x; v.y += p.y; v.z += p.z; v.w += p.w;
    }
    const int col = (int)(i4 % N);
    if (bias) {
        const float4 bv = *(const float4*)(bias + col);
        v.x += bv.x; v.y += bv.y; v.z += bv.z; v.w += bv.w;
    }
    if (act) {
        v.x = 0.5f * v.x * (1.f + erff(v.x * 0.70710678118f));
        v.y = 0.5f * v.y * (1.f + erff(v.y * 0.70710678118f));
        v.z = 0.5f * v.z * (1.f + erff(v.z * 0.70710678118f));
        v.w = 0.5f * v.w * (1.f + erff(v.w * 0.70710678118f));
    }
    if (resid) {
        const float4 rv = *(const float4*)(resid + i4);
        v.x += rv.x; v.y += rv.y; v.z += rv.z; v.w += rv.w;
    }
    if (Cf) *(float4*)(Cf + i4) = v;
    else {
        bf16x4 o; o[0] = (bf16)v.x; o[1] = (bf16)v.y; o[2] = (bf16)v.z; o[3] = (bf16)v.w;
        *(bf16x4*)(Cb + i4) = o;
    }
}

// ---------------- flash attention v4: balanced causal pairing ----------------
// Grid (32, Hz, Bz). Block pr handles 32-row q-tiles {pr, 63-pr} sequentially:
// key-iteration count ceil((pr+1)/4)+ceil((64-pr)/4) == 17 for every block ->
// perfectly uniform work across all 1024 resident blocks (4/CU).
// Waves: wq = q-half (16 rows), ws = key-half of the 128-key staged tile.
// Block stages K[128][64] + V^T[64][128] per iter via global_load_lds (XOR
// slot swizzle); ws halves merged via (aliased) LDS at end of each tile.
__global__ __launch_bounds__(256) void k_attn(const bf16* __restrict__ qkv,
                                              const bf16* __restrict__ Vt,
                                              bf16* __restrict__ ctx)
{
    __shared__ __align__(16) char smem[34816];
    bf16* lK = (bf16*)smem;             // [128 rows][64 elems]
    bf16* lV = (bf16*)(smem + 16384);   // [64 rows][128 elems]
    f32x4* sAcc = (f32x4*)smem;         // [wq][vt][lane]  (aliases lK)
    float*  sM  = (float*)(smem + 32768);
    float*  sL  = (float*)(smem + 33792);

    const int tid = threadIdx.x, lane = tid & 63, w = tid >> 6;
    const int l16 = lane & 15, quad = lane >> 4;
    const int wq = w & 1, ws = w >> 1;
    const int pr = blockIdx.x;                   // pair index 0..31
    const int h = blockIdx.y, b = blockIdx.z;

    const bf16* Qp  = qkv + (size_t)b * Tz * 3072 + h * 64;
    const bf16* Kp  = Qp + 1024;
    const bf16* Vtp = Vt + (size_t)(b * Hz + h) * 64 * Tz;

    const int krow  = tid >> 3;
    const int kslot = (tid & 7) ^ (krow & 7);
    const bf16* Kg = Kp + (size_t)krow * 3072 + kslot * 8;
    const int vrow  = tid >> 4;
    const int vslot = (tid & 15) ^ (vrow & 7);
    const bf16* Vg = Vtp + (size_t)vrow * Tz + vslot * 8;

#pragma unroll
    for (int ti = 0; ti < 2; ti++) {
        const int t = ti ? (63 - pr) : pr;       // 32-row q-tile index
        const int q0 = t * 32 + wq * 16;         // this wave's 16 q rows

        bf16x8 qf[2];
#pragma unroll
        for (int kh = 0; kh < 2; kh++)
            qf[kh] = *(const bf16x8*)(Qp + (size_t)(q0 + l16) * 3072 + kh*32 + quad*8);

        f32x4 acc[4] = {};
        float m = -1e30f, l = 0.f;

        const int keyEnd = t * 32 + 32;
        for (int ktB = 0; ktB < keyEnd; ktB += 128) {
            __syncthreads();                     // staging vs prior compute/merge
#pragma unroll
            for (int s = 0; s < 4; s++) {
                gl2lds16(Kg + (size_t)(ktB + s * 32) * 3072, lK + s * 2048 + w * 512);
                gl2lds16(Vg + (size_t)s * 16 * Tz + ktB,     lV + s * 2048 + w * 512);
            }
            __syncthreads();

            const int kt = ktB + ws * 64;
            if (kt <= q0 + 15) {                 // wave-uniform causal skip
                f32x4 sv[4];
                const int sw = l16 & 7;
#pragma unroll
                for (int c = 0; c < 4; c++) {
                    const int R = ws * 64 + c * 16 + l16;
                    bf16x8 kf0 = *(const bf16x8*)(lK + R * 64 + ((quad     ^ sw) * 8));
                    bf16x8 kf1 = *(const bf16x8*)(lK + R * 64 + (((4+quad) ^ sw) * 8));
                    f32x4 z = {0.f, 0.f, 0.f, 0.f};
                    z = __builtin_amdgcn_mfma_f32_16x16x32_bf16(kf0, qf[0], z, 0, 0, 0);
                    z = __builtin_amdgcn_mfma_f32_16x16x32_bf16(kf1, qf[1], z, 0, 0, 0);
                    sv[c] = z;
                }
                if (kt + 63 > q0) {              // mask only on diagonal tiles
#pragma unroll
                    for (int c = 0; c < 4; c++)
#pragma unroll
                        for (int r = 0; r < 4; r++)
                            if (kt + c*16 + quad*4 + r > q0 + l16) sv[c][r] = -1e30f;
                }
                float t0 = fmaxf(fmaxf(sv[0][0], sv[0][1]), fmaxf(sv[0][2], sv[0][3]));
                float t1 = fmaxf(fmaxf(sv[1][0], sv[1][1]), fmaxf(sv[1][2], sv[1][3]));
                float t2 = fmaxf(fmaxf(sv[2][0], sv[2][1]), fmaxf(sv[2][2], sv[2][3]));
                float t3 = fmaxf(fmaxf(sv[3][0], sv[3][1]), fmaxf(sv[3][2], sv[3][3]));
                float tm = fmaxf(fmaxf(t0, t1), fmaxf(t2, t3));
                tm = fmaxf(tm, __shfl_xor(tm, 16));
                tm = fmaxf(tm, __shfl_xor(tm, 32));
                if (__any(tm > m)) {
                    const float mn = fmaxf(m, tm);
                    const float a  = __expf(m - mn);
                    m = mn;
                    l *= a;
#pragma unroll
                    for (int vt = 0; vt < 4; vt++)
#pragma unroll
                        for (int r = 0; r < 4; r++) acc[vt][r] *= a;
                }
                float ts = 0.f;
#pragma unroll
                for (int c = 0; c < 4; c++) {
                    s16x4 vf[4];
                    const int gslot = ws * 8 + c * 2 + (quad >> 1);
#pragma unroll
                    for (int vt = 0; vt < 4; vt++) {
                        const int Rv = vt * 16 + l16;
                        vf[vt] = *(const s16x4*)(lV + Rv * 128 + ((gslot ^ (Rv & 7)) * 8)
                                                 + (quad & 1) * 4);
                    }
                    bf16x4 tb;
#pragma unroll
                    for (int r = 0; r < 4; r++) {
                        const float p = __expf(sv[c][r] - m);
                        ts += p;
                        tb[r] = (bf16)p;
                    }
                    const s16x4 pb = __builtin_bit_cast(s16x4, tb);
#pragma unroll
                    for (int vt = 0; vt < 4; vt++)
                        acc[vt] = __builtin_amdgcn_mfma_f32_16x16x16bf16_1k(
                            vf[vt], pb, acc[vt], 0, 0, 0);
                }
                ts += __shfl_xor(ts, 16);
                ts += __shfl_xor(ts, 32);
                l += ts;
            }
        }

        // merge ws halves (LDS aliased onto staging buffers)
        __syncthreads();
        if (ws == 1) {
            sM[wq * 64 + lane] = m;
            sL[wq * 64 + lane] = l;
#pragma unroll
            for (int vt = 0; vt < 4; vt++)
                sAcc[(wq * 4 + vt) * 64 + lane] = acc[vt];
        }
        __syncthreads();
        if (ws == 0) {
            const float m1 = sM[wq * 64 + lane], l1 = sL[wq * 64 + lane];
            const float M  = fmaxf(m, m1);
            const float a0 = __expf(m - M), a1 = __expf(m1 - M);
            const float inv = 1.f / (l * a0 + l1 * a1);
#pragma unroll
            for (int vt = 0; vt < 4; vt++) {
                const f32x4 o1 = sAcc[(wq * 4 + vt) * 64 + lane];
                bf16x4 o;
#pragma unroll
                for (int r = 0; r < 4; r++)
                    o[r] = (bf16)((acc[vt][r] * a0 + o1[r] * a1) * inv);
                *(bf16x4*)(ctx + (size_t)(b * Tz + q0 + l16) * 1024
                           + h * 64 + vt * 16 + quad * 4) = o;
            }
        }
    }
}

// ---------------- driver ----------------
extern "C" void kernel_launch(void* const* d_in, const int* in_sizes, int n_in,
                              void* d_out, int out_size, void* d_ws, size_t ws_size,
                              hipStream_t stream)
{
    const float* x     = (const float*)d_in[0];
    const float* w_q   = (const float*)d_in[1];
    const float* w_k   = (const float*)d_in[2];
    const float* w_v   = (const float*)d_in[3];
    const float* w_o   = (const float*)d_in[4];
    const float* b_o   = (const float*)d_in[5];
    const float* w_fc1 = (const float*)d_in[6];
    const float* b_fc1 = (const float*)d_in[7];
    const float* w_fc2 = (const float*)d_in[8];
    const float* b_fc2 = (const float*)d_in[9];
    const float* ln1_g = (const float*)d_in[10];
    const float* ln1_b = (const float*)d_in[11];
    const float* ln2_g = (const float*)d_in[12];
    const float* ln2_b = (const float*)d_in[13];
    float* out = (float*)d_out;

    char* p = (char*)d_ws;
    bf16* wqkvT = (bf16*)p; p += (size_t)3072 * 1024 * 2;
    bf16* woT   = (bf16*)p; p += (size_t)1024 * 1024 * 2;
    bf16* wfc1T = (bf16*)p; p += (size_t)4096 * 1024 * 2;
    bf16* wfc2T = (bf16*)p; p += (size_t)1024 * 4096 * 2;
    bf16* h1    = (bf16*)p; p += (size_t)NR * 1024 * 2;   // reused: Vt, then FC2 partials
    bf16* qkv   = (bf16*)p; p += (size_t)NR * 3072 * 2;   // FC2 partials tail
    bf16* ctx   = (bf16*)p; p += (size_t)NR * 1024 * 2;
    float* y    = (float*)p; p += (size_t)NR * 1024 * 4;
    bf16* h2    = (bf16*)p; p += (size_t)NR * 1024 * 2;
    bf16* g     = (bf16*)p; p += (size_t)NR * 4096 * 2;   // reused: proj partials
    bf16* Vt    = h1;
    float* projPart = (float*)g;    // 2 * 4096*1024*4 B = 33.55 MB == sizeof(g)
    float* fc2Part  = (float*)h1;   // 33.55 MB == sizeof(h1)+sizeof(qkv)

    const dim3 tb(32, 8);
    k_transpose_cvt<<<dim3(32, 32),  tb, 0, stream>>>(w_q,   wqkvT,             1024, 1024, 0.125f);
    k_transpose_cvt<<<dim3(32, 32),  tb, 0, stream>>>(w_k,   wqkvT + 1024*1024, 1024, 1024, 1.f);
    k_transpose_cvt<<<dim3(32, 32),  tb, 0, stream>>>(w_v,   wqkvT + 2048*1024, 1024, 1024, 1.f);
    k_transpose_cvt<<<dim3(32, 32),  tb, 0, stream>>>(w_o,   woT,               1024, 1024, 1.f);
    k_transpose_cvt<<<dim3(128, 32), tb, 0, stream>>>(w_fc1, wfc1T,             1024, 4096, 1.f);
    k_transpose_cvt<<<dim3(32, 128), tb, 0, stream>>>(w_fc2, wfc2T,             4096, 1024, 1.f);

    k_layernorm<<<NR, 256, 0, stream>>>(x, ln1_g, ln1_b, h1);
    k_gemm<<<dim3(3072/128, NR/128), 256, 0, stream>>>(h1, wqkvT, NR, 3072, 1024,
                                                       nullptr, nullptr, nullptr, qkv, 0,
                                                       nullptr, 1);
    k_vtrans<<<dim3(Tz/64, Bz*Hz), 256, 0, stream>>>(qkv, Vt);
    k_attn<<<dim3(32, Hz, Bz), 256, 0, stream>>>(qkv, Vt, ctx);

    // out-proj: split-K=2 -> partials in g, reduce fuses +b_o +x -> y (f32)
    k_gemm<<<dim3(1024/128, NR/128, 2), 256, 0, stream>>>(ctx, woT, NR, 1024, 1024,
                                                          nullptr, nullptr, nullptr, nullptr, 0,
                                                          projPart, 2);
    k_reduce<<<(size_t)NR * 1024 / 1024, 256, 0, stream>>>(projPart, 2, (size_t)NR * 1024, 1024,
                                                           b_o, x, y, nullptr, 0);

    k_layernorm<<<NR, 256, 0, stream>>>(y, ln2_g, ln2_b, h2);
    k_gemm<<<dim3(4096/128, NR/128), 256, 0, stream>>>(h2, wfc1T, NR, 4096, 1024,
                                                       b_fc1, nullptr, nullptr, g, 1,
                                                       nullptr, 1);
    // FC2: split-K=2 -> partials in h1+qkv, reduce fuses +b_fc2 +y -> out (f32)
    k_gemm<<<dim3(1024/128, NR/128, 2), 256, 0, stream>>>(g, wfc2T, NR, 1024, 4096,
                                                          nullptr, nullptr, nullptr, nullptr, 0,
                                                          fc2Part, 2);
    k_reduce<<<(size_t)NR * 1024 / 1024, 256, 0, stream>>>(fc2Part, 2, (size_t)NR * 1024, 1024,
                                                           b_fc2, y, out, nullptr, 0);
    (void)in_sizes; (void)n_in; (void)out_size; (void)ws_size;
}